// Round 19
// baseline (2130.946 us; speedup 1.0000x reference)
//
#include <hip/hip_runtime.h>
#include <hip/hip_bf16.h>

typedef __bf16 bf16_t;
typedef bf16_t bf16x8 __attribute__((ext_vector_type(8)));
typedef float f32x4 __attribute__((ext_vector_type(4)));

#define D_DIM 300
#define HSTRIDE 304   // bf16 h2 rows padded to 304 elems (608 B)
#define CSTRIDE 304   // combo table rows padded to 304 floats
#define ROWU 152      // bf16 h row = 152 u32 (304 bf16)
#define AROWU 160     // bf16 agg row = 160 u32 (320 bf16, 640 B)
#define TPB 320

__device__ inline f32x4 mfma16(bf16x8 a, bf16x8 b, f32x4 c) {
  return __builtin_amdgcn_mfma_f32_16x16x32_bf16(a, b, c, 0, 0, 0);
}

__device__ inline void split2(float x, unsigned short& h, unsigned short& l) {
  bf16_t hb = (bf16_t)x;
  float hf = (float)hb;
  bf16_t lb = (bf16_t)(x - hf);
  h = __builtin_bit_cast(unsigned short, hb);
  l = __builtin_bit_cast(unsigned short, lb);
}

__device__ inline uint4 pack8(const unsigned short* s) {
  return make_uint4((unsigned int)s[0] | ((unsigned int)s[1] << 16),
                    (unsigned int)s[2] | ((unsigned int)s[3] << 16),
                    (unsigned int)s[4] | ((unsigned int)s[5] << 16),
                    (unsigned int)s[6] | ((unsigned int)s[7] << 16));
}

__device__ inline unsigned int packbf2(float x0, float x1) {
  unsigned short a = __builtin_bit_cast(unsigned short, (bf16_t)x0);
  unsigned short b = __builtin_bit_cast(unsigned short, (bf16_t)x1);
  return (unsigned int)a | ((unsigned int)b << 16);
}

__device__ inline float bfu_lo(unsigned int u) {
  unsigned int x = u << 16;
  float f;
  __builtin_memcpy(&f, &x, 4);
  return f;
}

__device__ inline float bfu_hi(unsigned int u) {
  unsigned int x = u & 0xffff0000u;
  float f;
  __builtin_memcpy(&f, &x, 4);
  return f;
}

__device__ inline float bf16tof(unsigned short us) {
  unsigned int x = (unsigned int)us << 16;
  float f;
  __builtin_memcpy(&f, &x, 4);
  return f;
}

// ---------------- utility ----------------

__global__ void zero_u32_kernel(unsigned int* __restrict__ p, long long n) {
  long long i = (long long)blockIdx.x * blockDim.x + threadIdx.x;
  long long s = (long long)gridDim.x * blockDim.x;
  for (; i < n; i += s) p[i] = 0u;
}

// ---------------- graph prep ----------------

__global__ void init_h_kernel(const int* __restrict__ atom, const int* __restrict__ chir,
                              const float* __restrict__ e1, const float* __restrict__ e2,
                              unsigned int* __restrict__ hb) {
  int n = blockIdx.x;
  int t = threadIdx.x;
  if (t >= ROWU) return;
  int d = t * 2;
  unsigned int out = 0u;
  if (d < D_DIM) {
    int a = atom[n], c = chir[n];
    float x0 = e1[a * D_DIM + d] + e2[c * D_DIM + d];
    float x1 = e1[a * D_DIM + d + 1] + e2[c * D_DIM + d + 1];
    out = packbf2(x0, x1);
  }
  hb[(size_t)n * ROWU + t] = out;
}

__global__ void combo_kernel(const float* __restrict__ ee1, const float* __restrict__ ee2,
                             float* __restrict__ ct) {
  int l = blockIdx.x / 13, c = blockIdx.x % 13;
  int d = threadIdx.x;
  if (d >= CSTRIDE) return;
  int bt = (c < 12) ? (c / 3) : 4;
  int bd = (c < 12) ? (c % 3) : 0;
  float v = 0.f;
  if (d < D_DIM)
    v = ee1[(size_t)(l * 5 + bt) * D_DIM + d] + ee2[(size_t)(l * 3 + bd) * D_DIM + d];
  ct[((size_t)(l * 13 + c)) * CSTRIDE + d] = v;
}

__global__ void edge_combo_kernel(const int* __restrict__ bt, const int* __restrict__ bd,
                                  int* __restrict__ ec, int E) {
  int e = blockIdx.x * blockDim.x + threadIdx.x;
  if (e < E) ec[e] = bt[e] * 3 + bd[e];
}

// ---------------- CSR build (parallel hierarchical scan) ----------------

__global__ void csr_count_kernel(const int* __restrict__ row, int* __restrict__ deg, int E) {
  int e = blockIdx.x * blockDim.x + threadIdx.x;
  if (e < E) atomicAdd(&deg[row[e]], 1);
}

#define SBLK 1024
__global__ void scan1_kernel(const int* __restrict__ deg, int* __restrict__ off,
                             int* __restrict__ btot, int n) {
  __shared__ int buf[SBLK];
  int t = threadIdx.x;
  int i = blockIdx.x * SBLK + t;
  int v = (i < n) ? deg[i] : 0;
  buf[t] = v;
  __syncthreads();
#pragma unroll
  for (int s = 1; s < SBLK; s <<= 1) {
    int add = (t >= s) ? buf[t - s] : 0;
    __syncthreads();
    buf[t] += add;
    __syncthreads();
  }
  if (i < n) off[i] = buf[t] - v;
  if (t == SBLK - 1) btot[blockIdx.x] = buf[t];
}

__global__ void scan2_kernel(int* __restrict__ btot, int* __restrict__ off, int n, int nb) {
  __shared__ int buf[128];
  int t = threadIdx.x;
  int v = (t < nb) ? btot[t] : 0;
  buf[t] = v;
  __syncthreads();
#pragma unroll
  for (int s = 1; s < 128; s <<= 1) {
    int add = (t >= s) ? buf[t - s] : 0;
    __syncthreads();
    buf[t] += add;
    __syncthreads();
  }
  if (t < nb) btot[t] = buf[t] - v;
  if (t == nb - 1) off[n] = buf[t];
}

__global__ void scan3_kernel(int* __restrict__ off, int* __restrict__ cur,
                             const int* __restrict__ btot, int n) {
  int i = blockIdx.x * SBLK + threadIdx.x;
  if (i < n) {
    int v = off[i] + btot[blockIdx.x];
    off[i] = v;
    cur[i] = v;
  }
}

// fill packed edge records: pck[p] = (col << 4) | ec   (col < 2^24, ec < 13)
__global__ void csr_fill_kernel(const int* __restrict__ row, const int* __restrict__ col,
                                const int* __restrict__ ec, int* __restrict__ cur,
                                unsigned int* __restrict__ pck, int E) {
  int e = blockIdx.x * blockDim.x + threadIdx.x;
  if (e < E) {
    int r = row[e];
    int p = atomicAdd(&cur[r], 1);
    pck[p] = ((unsigned int)col[e] << 4) | (unsigned int)ec[e];
  }
}

// ---------------- graph segment offsets (batch is SORTED) ----------------

__global__ void goff_kernel(const int* __restrict__ batch, int* __restrict__ goff, int N, int G) {
  int n = blockIdx.x * blockDim.x + threadIdx.x;
  if (n >= N) return;
  if (n == 0) {
    int g1 = batch[0];
    for (int g = 0; g <= g1; ++g) goff[g] = 0;
  } else {
    int g0 = batch[n - 1], g1 = batch[n];
    for (int g = g0 + 1; g <= g1; ++g) goff[g] = n;
  }
  if (n == N - 1) {
    int g0 = batch[N - 1];
    for (int g = g0 + 1; g <= G; ++g) goff[g] = N;
  }
}

// ---------------- gather v4: bf16 h2 rows + folded BN-affine/relu ----------------
// TRANS=false (layer 0): x = raw bf16 h. TRANS=true: x = relu(fma(x, sc, sh)).
// One dwordx4 per edge-row (38 active lanes cover the 608 B row).

template <bool TRANS>
__global__ __launch_bounds__(256) void gather_kernel(
    const unsigned int* __restrict__ hb, const float* __restrict__ sc,
    const float* __restrict__ sh, const int* __restrict__ off,
    const unsigned int* __restrict__ pck, const float* __restrict__ ct_l,
    unsigned int* __restrict__ agg, int N) {
  int wid = threadIdx.x >> 6;
  int lane = threadIdx.x & 63;
  int n = blockIdx.x * 4 + wid;
  if (n >= N) return;
  const bool act = lane < 38;
  const int u4 = lane * 4;

  float scv[8], shv[8];
  if constexpr (TRANS) {
    if (act) {
      float4 s0 = ((const float4*)(sc + lane * 8))[0];
      float4 s1 = ((const float4*)(sc + lane * 8))[1];
      float4 t0 = ((const float4*)(sh + lane * 8))[0];
      float4 t1 = ((const float4*)(sh + lane * 8))[1];
      scv[0] = s0.x; scv[1] = s0.y; scv[2] = s0.z; scv[3] = s0.w;
      scv[4] = s1.x; scv[5] = s1.y; scv[6] = s1.z; scv[7] = s1.w;
      shv[0] = t0.x; shv[1] = t0.y; shv[2] = t0.z; shv[3] = t0.w;
      shv[4] = t1.x; shv[5] = t1.y; shv[6] = t1.z; shv[7] = t1.w;
    }
  }

  float a0[4] = {0.f, 0.f, 0.f, 0.f};
  float a1[4] = {0.f, 0.f, 0.f, 0.f};

#define ACCROW(HV, CP)                                                        \
  do {                                                                        \
    float4 ca = ((const float4*)(CP))[0];                                     \
    float4 cb = ((const float4*)(CP))[1];                                     \
    float xl, xh;                                                             \
    xl = bfu_lo((HV).x); xh = bfu_hi((HV).x);                                 \
    if constexpr (TRANS) {                                                    \
      xl = fmaxf(fmaf(xl, scv[0], shv[0]), 0.f);                              \
      xh = fmaxf(fmaf(xh, scv[1], shv[1]), 0.f);                              \
    }                                                                         \
    a0[0] += xl + ca.x; a1[0] += xh + ca.y;                                   \
    xl = bfu_lo((HV).y); xh = bfu_hi((HV).y);                                 \
    if constexpr (TRANS) {                                                    \
      xl = fmaxf(fmaf(xl, scv[2], shv[2]), 0.f);                              \
      xh = fmaxf(fmaf(xh, scv[3], shv[3]), 0.f);                              \
    }                                                                         \
    a0[1] += xl + ca.z; a1[1] += xh + ca.w;                                   \
    xl = bfu_lo((HV).z); xh = bfu_hi((HV).z);                                 \
    if constexpr (TRANS) {                                                    \
      xl = fmaxf(fmaf(xl, scv[4], shv[4]), 0.f);                              \
      xh = fmaxf(fmaf(xh, scv[5], shv[5]), 0.f);                              \
    }                                                                         \
    a0[2] += xl + cb.x; a1[2] += xh + cb.y;                                   \
    xl = bfu_lo((HV).w); xh = bfu_hi((HV).w);                                 \
    if constexpr (TRANS) {                                                    \
      xl = fmaxf(fmaf(xl, scv[6], shv[6]), 0.f);                              \
      xh = fmaxf(fmaf(xh, scv[7], shv[7]), 0.f);                              \
    }                                                                         \
    a0[3] += xl + cb.z; a1[3] += xh + cb.w;                                   \
  } while (0)

  if (act) {
    uint4 hv = *(const uint4*)(hb + (size_t)n * ROWU + u4);
    ACCROW(hv, ct_l + 12 * CSTRIDE + lane * 8);
  }

  int p0 = off[n], p1 = off[n + 1];
  int p = p0;
  for (; p + 2 <= p1; p += 2) {
    unsigned int k0 = pck[p];
    unsigned int k1 = pck[p + 1];
    if (act) {
      uint4 h0 = *(const uint4*)(hb + (size_t)(k0 >> 4) * ROWU + u4);
      uint4 h1 = *(const uint4*)(hb + (size_t)(k1 >> 4) * ROWU + u4);
      ACCROW(h0, ct_l + (k0 & 15u) * CSTRIDE + lane * 8);
      ACCROW(h1, ct_l + (k1 & 15u) * CSTRIDE + lane * 8);
    }
  }
  if (p < p1) {
    unsigned int k0 = pck[p];
    if (act) {
      uint4 h0 = *(const uint4*)(hb + (size_t)(k0 >> 4) * ROWU + u4);
      ACCROW(h0, ct_l + (k0 & 15u) * CSTRIDE + lane * 8);
    }
  }
#undef ACCROW

  unsigned int* ao = agg + (size_t)n * AROWU;
  if (act) {
    uint4 o;
    o.x = packbf2(a0[0], a1[0]);
    o.y = packbf2(a0[1], a1[1]);
    o.z = packbf2(a0[2], a1[2]);
    o.w = packbf2(a0[3], a1[3]);
    *(uint4*)(ao + u4) = o;
  } else if (lane < 40) {
    *(uint4*)(ao + u4) = make_uint4(0, 0, 0, 0);
  }
}

// ---------------- BN final ----------------

__global__ void bn_final_kernel(const float* __restrict__ stats, const float* __restrict__ gamma_l,
                                const float* __restrict__ beta_l, float* __restrict__ bnsc,
                                float* __restrict__ bnsh, int N) {
  int d = threadIdx.x;
  if (d >= D_DIM) return;
  float inv_n = 1.0f / (float)N;
  float mean = stats[d] * inv_n;
  float var = stats[D_DIM + d] * inv_n - mean * mean;
  float inv = rsqrtf(var + 1e-5f);
  float sc = gamma_l[d] * inv;
  bnsc[d] = sc;
  bnsh[d] = beta_l[d] - mean * sc;
}

// ---------------- pooling: segmented reduction over sorted batch, bf16 h2 ----

__global__ void pool_seg_kernel(const unsigned short* __restrict__ h2b,
                                const float* __restrict__ sc, const float* __restrict__ sh,
                                const int* __restrict__ goff, float* __restrict__ pool) {
  int g = blockIdx.x;
  int d = threadIdx.x;
  if (d >= D_DIM) return;
  int s = goff[g], e = goff[g + 1];
  float scv = sc[d], shv = sh[d];
  float acc = 0.f;
  for (int n = s; n < e; ++n) acc += fmaf(bf16tof(h2b[(size_t)n * HSTRIDE + d]), scv, shv);
  float cnt = (float)(e - s);
  if (cnt < 1.f) cnt = 1.f;
  pool[(size_t)g * D_DIM + d] = acc / cnt;
}

// ---------------- weight pack ----------------

__global__ void wpack_kernel(const float* __restrict__ W, bf16_t* __restrict__ Th,
                             bf16_t* __restrict__ Tl, int K, int Nw) {
  int ct = blockIdx.x;
  int ks = blockIdx.y;
  int l = threadIdx.x;
  int col = ct * 16 + (l & 15);
  int kb = ks * 32 + (l >> 4) * 8;
  unsigned short hs[8], ls[8];
#pragma unroll
  for (int j = 0; j < 8; ++j) {
    int k = kb + j;
    float v = (k < K && col < Nw) ? W[(size_t)k * Nw + col] : 0.f;
    split2(v, hs[j], ls[j]);
  }
  size_t off = ((size_t)(ct * gridDim.y + ks) * 64 + l) * 8;
  *(uint4*)(Th + off) = pack8(hs);
  *(uint4*)(Tl + off) = pack8(ls);
}

// ---------------- MFMA GEMM v10 (round-14 proven): raw barrier + B-reg dbuf ----

template <int KP, int KV, bool RELU, bool OUT_BF16, bool STATS>
__global__ __launch_bounds__(256, 4) void mfma_gemm10(
    const unsigned short* __restrict__ A, const bf16_t* __restrict__ Bh,
    const bf16_t* __restrict__ Bl, const float* __restrict__ bias, void* __restrict__ Cptr,
    float* __restrict__ stats, int M, int Nc, int astride, int cstride, int nx, int nyT) {
  constexpr int KSTEPS = KP / 32;
  constexpr int PLANE = 128 * 80;
  __shared__ __align__(16) char lds[2 * PLANE];

  int dd = blockIdx.x;
  int xcd = dd & 7;
  int q = dd >> 3;
  int xt = q % nx;
  int yt = (q / nx) * 8 + xcd;
  if (yt >= nyT) return;
  const int m0 = yt * 128;
  const int n0 = xt * 64;
  const int nb16 = n0 >> 4;

  const int t = threadIdx.x;
  const int w = t >> 6;
  const int lane = t & 63;
  const int wm = w >> 1, wn = w & 1;
  const int lrow = lane & 15;
  const int lk = lane >> 4;

  const int sr = t >> 1;
  const int skh = (t & 1) * 16;
  int gr = m0 + sr;
  if (gr >= M) gr = M - 1;
  const unsigned short* arow = A + (size_t)gr * astride + skh;
  const int soff = sr * 80 + (t & 1) * 32;

  const bf16_t* bp0h = Bh + ((size_t)(nb16 + wn * 2 + 0) * KSTEPS * 64 + lane) * 8;
  const bf16_t* bp1h = Bh + ((size_t)(nb16 + wn * 2 + 1) * KSTEPS * 64 + lane) * 8;
  const bf16_t* bp0l = Bl + ((size_t)(nb16 + wn * 2 + 0) * KSTEPS * 64 + lane) * 8;
  const bf16_t* bp1l = Bl + ((size_t)(nb16 + wn * 2 + 1) * KSTEPS * 64 + lane) * 8;

  f32x4 acc[4][2] = {};

  {
    uint4 v0 = ((const uint4*)arow)[0];
    uint4 v1 = ((const uint4*)arow)[1];
    *(uint4*)(lds + soff) = v0;
    *(uint4*)(lds + soff + 16) = v1;
  }
  bf16x8 bhc0 = *(const bf16x8*)(const void*)bp0h;
  bf16x8 bhc1 = *(const bf16x8*)(const void*)bp1h;
  bf16x8 blc0 = *(const bf16x8*)(const void*)bp0l;
  bf16x8 blc1 = *(const bf16x8*)(const void*)bp1l;
  __builtin_amdgcn_sched_barrier(0);
  asm volatile("s_waitcnt lgkmcnt(0)");
  __builtin_amdgcn_s_barrier();
  __builtin_amdgcn_sched_barrier(0);

#pragma unroll
  for (int kt = 0; kt < KSTEPS; ++kt) {
    const int cur = kt & 1;
    uint4 n0v, n1v;
    bf16x8 bhn0, bhn1, bln0, bln1;
    if (kt + 1 < KSTEPS) {
      const uint4* p = (const uint4*)(arow + (kt + 1) * 32);
      n0v = p[0];
      n1v = p[1];
      if (KV < KP) {
        int kg = (kt + 1) * 32 + skh;
        if (kg >= KV) n0v = make_uint4(0, 0, 0, 0);
        if (kg + 8 >= KV) n1v = make_uint4(0, 0, 0, 0);
      }
      int bs = (kt + 1) * 512;
      bhn0 = *(const bf16x8*)(const void*)(bp0h + bs);
      bhn1 = *(const bf16x8*)(const void*)(bp1h + bs);
      bln0 = *(const bf16x8*)(const void*)(bp0l + bs);
      bln1 = *(const bf16x8*)(const void*)(bp1l + bs);
    }
    const char* lbase = lds + cur * PLANE;
    bf16x8 ah[4];
#pragma unroll
    for (int i = 0; i < 4; ++i) {
      int row = wm * 64 + i * 16 + lrow;
      ah[i] = *(const bf16x8*)(const void*)(lbase + row * 80 + lk * 16);
    }
#pragma unroll
    for (int i = 0; i < 4; ++i) {
      acc[i][0] = mfma16(ah[i], bhc0, acc[i][0]);
      acc[i][0] = mfma16(ah[i], blc0, acc[i][0]);
      acc[i][1] = mfma16(ah[i], bhc1, acc[i][1]);
      acc[i][1] = mfma16(ah[i], blc1, acc[i][1]);
    }
    if (kt + 1 < KSTEPS) {
      char* sn = lds + (cur ^ 1) * PLANE + soff;
      *(uint4*)(sn) = n0v;
      *(uint4*)(sn + 16) = n1v;
      __builtin_amdgcn_sched_barrier(0);
      asm volatile("s_waitcnt lgkmcnt(0)");
      __builtin_amdgcn_s_barrier();
      __builtin_amdgcn_sched_barrier(0);
      bhc0 = bhn0;
      bhc1 = bhn1;
      blc0 = bln0;
      blc1 = bln1;
    }
  }

#pragma unroll
  for (int j = 0; j < 2; ++j) {
    int gcol = n0 + wn * 32 + j * 16 + lrow;
    bool colok = gcol < Nc;
    float bsv = colok ? bias[gcol] : 0.f;
    float s = 0.f, s2 = 0.f;
#pragma unroll
    for (int i = 0; i < 4; ++i) {
#pragma unroll
      for (int r4 = 0; r4 < 4; ++r4) {
        int grow = m0 + wm * 64 + i * 16 + lk * 4 + r4;
        if (grow < M && colok) {
          float v = acc[i][j][r4] + bsv;
          if (RELU) v = fmaxf(v, 0.f);
          if constexpr (STATS) {
            s += v;
            s2 += v * v;
          }
          if constexpr (OUT_BF16)
            ((bf16_t*)Cptr)[(size_t)grow * cstride + gcol] = (bf16_t)v;
          else
            ((float*)Cptr)[(size_t)grow * cstride + gcol] = v;
        }
      }
    }
    if constexpr (STATS) {
      s += __shfl_xor(s, 16);
      s += __shfl_xor(s, 32);
      s2 += __shfl_xor(s2, 16);
      s2 += __shfl_xor(s2, 32);
      if (lk == 0 && colok) {
        atomicAdd(&stats[gcol], s);
        atomicAdd(&stats[D_DIM + gcol], s2);
      }
    }
  }
}

// ---------------- MFMA GEMM v6 (LDS path, fp32-A feat/proj only) ----------------

template <int KP, bool RELU, bool OUT_BF16>
__global__ __launch_bounds__(256, 4) void mfma_gemm6(
    const char* __restrict__ A0, const bf16_t* __restrict__ Bh, const bf16_t* __restrict__ Bl,
    const float* __restrict__ bias, void* __restrict__ Cptr, int M, int Nc, int K, int abytes,
    int cstride, int nx, int nyT) {
  constexpr int KSTEPS = KP / 32;
  constexpr int PLANE = 128 * 80;
  __shared__ __align__(16) char lds[2 * PLANE];

  int dd = blockIdx.x;
  int xcd = dd & 7;
  int q = dd >> 3;
  int xt = q % nx;
  int yt = (q / nx) * 8 + xcd;
  if (yt >= nyT) return;
  const int m0 = yt * 128;
  const int n0 = xt * 64;
  const int nb16 = n0 >> 4;

  const int t = threadIdx.x;
  const int w = t >> 6;
  const int lane = t & 63;
  const int wm = w >> 1, wn = w & 1;
  const int lrow = lane & 15;
  const int lk = lane >> 4;

  const int sr = t >> 1;
  const int skh = (t & 1) * 16;
  const int gr = m0 + sr;
  char* sdst = lds + sr * 80 + (t & 1) * 32;

  f32x4 acc[4][2] = {};

  for (int kt = 0; kt < KSTEPS; ++kt) {
    const int kg = kt * 32 + skh;
    float va[16];
    if (gr < M && kg + 16 <= K) {
      const float4* fp = (const float4*)(A0 + (size_t)gr * abytes + kg * 4);
#pragma unroll
      for (int qd = 0; qd < 4; ++qd) {
        float4 x = fp[qd];
        va[4 * qd] = x.x;
        va[4 * qd + 1] = x.y;
        va[4 * qd + 2] = x.z;
        va[4 * qd + 3] = x.w;
      }
    } else {
#pragma unroll
      for (int j = 0; j < 16; ++j)
        va[j] = (gr < M && kg + j < K) ? *(const float*)(A0 + (size_t)gr * abytes + (kg + j) * 4)
                                       : 0.f;
    }
    unsigned short hs[16], ls[16];
#pragma unroll
    for (int j = 0; j < 16; ++j) split2(va[j], hs[j], ls[j]);
    *(uint4*)(sdst) = pack8(hs);
    *(uint4*)(sdst + 16) = pack8(hs + 8);
    *(uint4*)(sdst + PLANE) = pack8(ls);
    *(uint4*)(sdst + PLANE + 16) = pack8(ls + 8);
    __syncthreads();
    bf16x8 ah[4], al[4];
#pragma unroll
    for (int i = 0; i < 4; ++i) {
      int row = wm * 64 + i * 16 + lrow;
      ah[i] = *(const bf16x8*)(const void*)(lds + row * 80 + lk * 16);
      al[i] = *(const bf16x8*)(const void*)(lds + PLANE + row * 80 + lk * 16);
    }
#pragma unroll
    for (int j = 0; j < 2; ++j) {
      int ct16 = nb16 + wn * 2 + j;
      size_t bo = ((size_t)(ct16 * KSTEPS + kt) * 64 + lane) * 8;
      bf16x8 bh = *(const bf16x8*)(const void*)(Bh + bo);
      bf16x8 bl = *(const bf16x8*)(const void*)(Bl + bo);
#pragma unroll
      for (int i = 0; i < 4; ++i) {
        acc[i][j] = mfma16(ah[i], bh, acc[i][j]);
        acc[i][j] = mfma16(ah[i], bl, acc[i][j]);
        acc[i][j] = mfma16(al[i], bh, acc[i][j]);
      }
    }
    __syncthreads();
  }

#pragma unroll
  for (int j = 0; j < 2; ++j) {
    int gcol = n0 + wn * 32 + j * 16 + lrow;
    if (gcol >= Nc) continue;
    float bsv = bias[gcol];
#pragma unroll
    for (int i = 0; i < 4; ++i) {
#pragma unroll
      for (int r4 = 0; r4 < 4; ++r4) {
        int grow = m0 + wm * 64 + i * 16 + lk * 4 + r4;
        if (grow < M) {
          float v = acc[i][j][r4] + bsv;
          if (RELU) v = fmaxf(v, 0.f);
          if constexpr (OUT_BF16)
            ((bf16_t*)Cptr)[(size_t)grow * cstride + gcol] = (bf16_t)v;
          else
            ((float*)Cptr)[(size_t)grow * cstride + gcol] = v;
        }
      }
    }
  }
}

// ---------------- launch ----------------

extern "C" void kernel_launch(void* const* d_in, const int* in_sizes, int n_in,
                              void* d_out, int out_size, void* d_ws, size_t ws_size,
                              hipStream_t stream) {
  const int* atom = (const int*)d_in[0];
  const int* chir = (const int*)d_in[1];
  const int* eidx = (const int*)d_in[2];
  const int* btype = (const int*)d_in[3];
  const int* bdir = (const int*)d_in[4];
  const int* batch = (const int*)d_in[5];
  const float* x_emb1 = (const float*)d_in[6];
  const float* x_emb2 = (const float*)d_in[7];
  const float* ee1 = (const float*)d_in[8];
  const float* ee2 = (const float*)d_in[9];
  const float* W1 = (const float*)d_in[10];
  const float* b1 = (const float*)d_in[11];
  const float* W2 = (const float*)d_in[12];
  const float* b2 = (const float*)d_in[13];
  const float* gamma = (const float*)d_in[14];
  const float* beta = (const float*)d_in[15];
  const float* featW = (const float*)d_in[16];
  const float* featb = (const float*)d_in[17];
  const float* projW = (const float*)d_in[18];
  const float* projb = (const float*)d_in[19];

  const int N = in_sizes[0];
  const int E = in_sizes[2] / 2;
  const int PROJ = in_sizes[19];
  const int FEAT = in_sizes[17];
  const int G = out_size / PROJ;
  const int L = in_sizes[11] / (2 * D_DIM);
  const int D2 = 2 * D_DIM;  // 600

  const int* row = eidx;
  const int* col = eidx + E;

  const int CT16_1 = 40, KS_1 = 10;  // W1: K=300->KP320, N=600->640
  const int CT16_2 = 20, KS_2 = 19;  // W2: K=600->KP608, N=300->320
  const int CT16_F = 32, KS_F = 10;  // feat
  const int CT16_P = 16, KS_P = 16;  // proj
  const int SZ1 = CT16_1 * KS_1 * 512;
  const int SZ2 = CT16_2 * KS_2 * 512;
  const int SZF = CT16_F * KS_F * 512;
  const int SZP = CT16_P * KS_P * 512;

  char* ws = (char*)d_ws;
  size_t off = 0;
  auto alloc = [&](size_t bytes) -> char* {
    char* p = ws + off;
    off += (bytes + 255) & ~(size_t)255;
    return p;
  };
  // disjoint per-phase buffers: gather R3->R1, GEMM1 R1->R2, GEMM2 R2->R3
  char* R1 = alloc((size_t)N * 640);   // agg bf16 [N][320]
  char* R2 = alloc((size_t)N * 1216);  // hid bf16 [N][608]
  char* R3 = alloc((size_t)N * 608);   // h2 bf16 [N][304]
  float* CT = (float*)alloc((size_t)L * 13 * CSTRIDE * 4);
  int* EC = (int*)alloc((size_t)E * 4);
  int* DEG = (int*)alloc((size_t)N * 4);
  int* OFF = (int*)alloc((size_t)(N + 1) * 4);
  int* CUR = (int*)alloc((size_t)N * 4);
  int* BTOT = (int*)alloc(512);
  unsigned int* PCK = (unsigned int*)alloc((size_t)E * 4);
  int* GOFF = (int*)alloc((size_t)(G + 1) * 4);
  float* STATS = (float*)alloc(2 * D_DIM * 4);
  float* BNSC = (float*)alloc(D_DIM * 4);
  float* BNSH = (float*)alloc(D_DIM * 4);
  bf16_t* W1Th = (bf16_t*)alloc((size_t)L * SZ1 * 2);
  bf16_t* W1Tl = (bf16_t*)alloc((size_t)L * SZ1 * 2);
  bf16_t* W2Th = (bf16_t*)alloc((size_t)L * SZ2 * 2);
  bf16_t* W2Tl = (bf16_t*)alloc((size_t)L * SZ2 * 2);
  bf16_t* FTh = (bf16_t*)alloc((size_t)SZF * 2);
  bf16_t* FTl = (bf16_t*)alloc((size_t)SZF * 2);
  bf16_t* PTh = (bf16_t*)alloc((size_t)SZP * 2);
  bf16_t* PTl = (bf16_t*)alloc((size_t)SZP * 2);
  (void)ws_size;

  unsigned int* AGG = (unsigned int*)R1;
  char* HID = R2;
  unsigned int* H2B = (unsigned int*)R3;

  // ---- prep ----
  init_h_kernel<<<N, 256, 0, stream>>>(atom, chir, x_emb1, x_emb2, H2B);
  combo_kernel<<<L * 13, TPB, 0, stream>>>(ee1, ee2, CT);
  edge_combo_kernel<<<(E + 255) / 256, 256, 0, stream>>>(btype, bdir, EC, E);

  const int nb = (N + SBLK - 1) / SBLK;
  zero_u32_kernel<<<(N + 255) / 256, 256, 0, stream>>>((unsigned int*)DEG, N);
  csr_count_kernel<<<(E + 255) / 256, 256, 0, stream>>>(row, DEG, E);
  scan1_kernel<<<nb, SBLK, 0, stream>>>(DEG, OFF, BTOT, N);
  scan2_kernel<<<1, 128, 0, stream>>>(BTOT, OFF, N, nb);
  scan3_kernel<<<nb, SBLK, 0, stream>>>(OFF, CUR, BTOT, N);
  csr_fill_kernel<<<(E + 255) / 256, 256, 0, stream>>>(row, col, EC, CUR, PCK, E);
  goff_kernel<<<(N + 255) / 256, 256, 0, stream>>>(batch, GOFF, N, G);

  for (int l = 0; l < L; ++l) {
    wpack_kernel<<<dim3(CT16_1, KS_1), 64, 0, stream>>>(
        W1 + (size_t)l * D_DIM * D2, W1Th + (size_t)l * SZ1, W1Tl + (size_t)l * SZ1, D_DIM, D2);
    wpack_kernel<<<dim3(CT16_2, KS_2), 64, 0, stream>>>(
        W2 + (size_t)l * D2 * D_DIM, W2Th + (size_t)l * SZ2, W2Tl + (size_t)l * SZ2, D2, D_DIM);
  }
  wpack_kernel<<<dim3(CT16_F, KS_F), 64, 0, stream>>>(featW, FTh, FTl, D_DIM, FEAT);
  wpack_kernel<<<dim3(CT16_P, KS_P), 64, 0, stream>>>(projW, PTh, PTl, FEAT, PROJ);

  const int nyT = (N + 127) / 128;
  const int ny8 = ((nyT + 7) / 8) * 8;
  const int nyG = (G + 127) / 128;
  const int nyG8 = ((nyG + 7) / 8) * 8;

  for (int l = 0; l < L; ++l) {
    const float* ctl = CT + (size_t)l * 13 * CSTRIDE;
    // gather: reads H2B (R3, bf16) + folded affine; writes agg (R1)
    if (l == 0)
      gather_kernel<false><<<(N + 3) / 4, 256, 0, stream>>>(H2B, BNSC, BNSH, OFF, PCK, ctl,
                                                            AGG, N);
    else
      gather_kernel<true><<<(N + 3) / 4, 256, 0, stream>>>(H2B, BNSC, BNSH, OFF, PCK, ctl,
                                                           AGG, N);
    // hid = relu(agg @ W1 + b1) -> bf16 [N][608] into R2
    mfma_gemm10<320, 320, true, true, false><<<10 * ny8, 256, 0, stream>>>(
        (const unsigned short*)R1, W1Th + (size_t)l * SZ1, W1Tl + (size_t)l * SZ1,
        b1 + (size_t)l * D2, HID, nullptr, N, D2, 320, 608, 10, nyT);
    // h2 = hid @ W2 + b2 -> bf16 [N][304] into R3, fused column stats (fp32)
    zero_u32_kernel<<<2, 320, 0, stream>>>((unsigned int*)STATS, 2 * D_DIM);
    mfma_gemm10<608, 600, false, true, true><<<5 * ny8, 256, 0, stream>>>(
        (const unsigned short*)HID, W2Th + (size_t)l * SZ2, W2Tl + (size_t)l * SZ2,
        b2 + (size_t)l * D_DIM, H2B, STATS, N, D_DIM, 608, HSTRIDE, 5, nyT);
    bn_final_kernel<<<1, TPB, 0, stream>>>(STATS, gamma + (size_t)l * D_DIM,
                                           beta + (size_t)l * D_DIM, BNSC, BNSH, N);
  }

  // final h2 bf16 in R3 (last BN folded into pool); R2 free
  float* POOL = (float*)R2;
  float* FEATB = POOL + (size_t)G * D_DIM;

  pool_seg_kernel<<<G, TPB, 0, stream>>>((const unsigned short*)H2B, BNSC, BNSH, GOFF, POOL);

  mfma_gemm6<320, false, false><<<8 * nyG8, 256, 0, stream>>>(
      (const char*)POOL, FTh, FTl, featb, FEATB, G, FEAT, D_DIM, 1200, FEAT, 8, nyG);
  mfma_gemm6<512, false, false><<<4 * nyG8, 256, 0, stream>>>(
      (const char*)FEATB, PTh, PTl, projb, d_out, G, PROJ, FEAT, 2048, PROJ, 4, nyG);
}

// Round 20
// 1923.592 us; speedup vs baseline: 1.1078x; 1.1078x over previous
//
#include <hip/hip_runtime.h>
#include <hip/hip_bf16.h>

typedef __bf16 bf16_t;
typedef bf16_t bf16x8 __attribute__((ext_vector_type(8)));
typedef float f32x4 __attribute__((ext_vector_type(4)));

#define D_DIM 300
#define HSTRIDE 304   // bf16 h2 rows padded to 304 elems (608 B)
#define CSTRIDE 304   // combo table rows padded to 304 floats
#define ROWU 152      // bf16 h row = 152 u32 (304 bf16)
#define AROWU 160     // bf16 agg row = 160 u32 (320 bf16, 640 B)
#define TPB 320

__device__ inline f32x4 mfma16(bf16x8 a, bf16x8 b, f32x4 c) {
  return __builtin_amdgcn_mfma_f32_16x16x32_bf16(a, b, c, 0, 0, 0);
}

__device__ inline void split2(float x, unsigned short& h, unsigned short& l) {
  bf16_t hb = (bf16_t)x;
  float hf = (float)hb;
  bf16_t lb = (bf16_t)(x - hf);
  h = __builtin_bit_cast(unsigned short, hb);
  l = __builtin_bit_cast(unsigned short, lb);
}

__device__ inline uint4 pack8(const unsigned short* s) {
  return make_uint4((unsigned int)s[0] | ((unsigned int)s[1] << 16),
                    (unsigned int)s[2] | ((unsigned int)s[3] << 16),
                    (unsigned int)s[4] | ((unsigned int)s[5] << 16),
                    (unsigned int)s[6] | ((unsigned int)s[7] << 16));
}

__device__ inline unsigned int packbf2(float x0, float x1) {
  unsigned short a = __builtin_bit_cast(unsigned short, (bf16_t)x0);
  unsigned short b = __builtin_bit_cast(unsigned short, (bf16_t)x1);
  return (unsigned int)a | ((unsigned int)b << 16);
}

__device__ inline float bfu_lo(unsigned int u) {
  unsigned int x = u << 16;
  float f;
  __builtin_memcpy(&f, &x, 4);
  return f;
}

__device__ inline float bfu_hi(unsigned int u) {
  unsigned int x = u & 0xffff0000u;
  float f;
  __builtin_memcpy(&f, &x, 4);
  return f;
}

__device__ inline float bf16tof(unsigned short us) {
  unsigned int x = (unsigned int)us << 16;
  float f;
  __builtin_memcpy(&f, &x, 4);
  return f;
}

// ---------------- utility ----------------

__global__ void zero_u32_kernel(unsigned int* __restrict__ p, long long n) {
  long long i = (long long)blockIdx.x * blockDim.x + threadIdx.x;
  long long s = (long long)gridDim.x * blockDim.x;
  for (; i < n; i += s) p[i] = 0u;
}

// ---------------- graph prep ----------------

__global__ void init_h_kernel(const int* __restrict__ atom, const int* __restrict__ chir,
                              const float* __restrict__ e1, const float* __restrict__ e2,
                              unsigned int* __restrict__ hb) {
  int n = blockIdx.x;
  int t = threadIdx.x;
  if (t >= ROWU) return;
  int d = t * 2;
  unsigned int out = 0u;
  if (d < D_DIM) {
    int a = atom[n], c = chir[n];
    float x0 = e1[a * D_DIM + d] + e2[c * D_DIM + d];
    float x1 = e1[a * D_DIM + d + 1] + e2[c * D_DIM + d + 1];
    out = packbf2(x0, x1);
  }
  hb[(size_t)n * ROWU + t] = out;
}

__global__ void combo_kernel(const float* __restrict__ ee1, const float* __restrict__ ee2,
                             float* __restrict__ ct) {
  int l = blockIdx.x / 13, c = blockIdx.x % 13;
  int d = threadIdx.x;
  if (d >= CSTRIDE) return;
  int bt = (c < 12) ? (c / 3) : 4;
  int bd = (c < 12) ? (c % 3) : 0;
  float v = 0.f;
  if (d < D_DIM)
    v = ee1[(size_t)(l * 5 + bt) * D_DIM + d] + ee2[(size_t)(l * 3 + bd) * D_DIM + d];
  ct[((size_t)(l * 13 + c)) * CSTRIDE + d] = v;
}

__global__ void edge_combo_kernel(const int* __restrict__ bt, const int* __restrict__ bd,
                                  int* __restrict__ ec, int E) {
  int e = blockIdx.x * blockDim.x + threadIdx.x;
  if (e < E) ec[e] = bt[e] * 3 + bd[e];
}

// ---------------- CSR build (parallel hierarchical scan) ----------------

__global__ void csr_count_kernel(const int* __restrict__ row, int* __restrict__ deg, int E) {
  int e = blockIdx.x * blockDim.x + threadIdx.x;
  if (e < E) atomicAdd(&deg[row[e]], 1);
}

#define SBLK 1024
__global__ void scan1_kernel(const int* __restrict__ deg, int* __restrict__ off,
                             int* __restrict__ btot, int n) {
  __shared__ int buf[SBLK];
  int t = threadIdx.x;
  int i = blockIdx.x * SBLK + t;
  int v = (i < n) ? deg[i] : 0;
  buf[t] = v;
  __syncthreads();
#pragma unroll
  for (int s = 1; s < SBLK; s <<= 1) {
    int add = (t >= s) ? buf[t - s] : 0;
    __syncthreads();
    buf[t] += add;
    __syncthreads();
  }
  if (i < n) off[i] = buf[t] - v;
  if (t == SBLK - 1) btot[blockIdx.x] = buf[t];
}

__global__ void scan2_kernel(int* __restrict__ btot, int* __restrict__ off, int n, int nb) {
  __shared__ int buf[128];
  int t = threadIdx.x;
  int v = (t < nb) ? btot[t] : 0;
  buf[t] = v;
  __syncthreads();
#pragma unroll
  for (int s = 1; s < 128; s <<= 1) {
    int add = (t >= s) ? buf[t - s] : 0;
    __syncthreads();
    buf[t] += add;
    __syncthreads();
  }
  if (t < nb) btot[t] = buf[t] - v;
  if (t == nb - 1) off[n] = buf[t];
}

__global__ void scan3_kernel(int* __restrict__ off, int* __restrict__ cur,
                             const int* __restrict__ btot, int n) {
  int i = blockIdx.x * SBLK + threadIdx.x;
  if (i < n) {
    int v = off[i] + btot[blockIdx.x];
    off[i] = v;
    cur[i] = v;
  }
}

// fill packed edge records: pck[p] = (col << 4) | ec   (col < 2^24, ec < 13)
__global__ void csr_fill_kernel(const int* __restrict__ row, const int* __restrict__ col,
                                const int* __restrict__ ec, int* __restrict__ cur,
                                unsigned int* __restrict__ pck, int E) {
  int e = blockIdx.x * blockDim.x + threadIdx.x;
  if (e < E) {
    int r = row[e];
    int p = atomicAdd(&cur[r], 1);
    pck[p] = ((unsigned int)col[e] << 4) | (unsigned int)ec[e];
  }
}

// ---------------- graph segment offsets (batch is SORTED) ----------------

__global__ void goff_kernel(const int* __restrict__ batch, int* __restrict__ goff, int N, int G) {
  int n = blockIdx.x * blockDim.x + threadIdx.x;
  if (n >= N) return;
  if (n == 0) {
    int g1 = batch[0];
    for (int g = 0; g <= g1; ++g) goff[g] = 0;
  } else {
    int g0 = batch[n - 1], g1 = batch[n];
    for (int g = g0 + 1; g <= g1; ++g) goff[g] = n;
  }
  if (n == N - 1) {
    int g0 = batch[N - 1];
    for (int g = g0 + 1; g <= G; ++g) goff[g] = N;
  }
}

// ---------------- gather v4: bf16 h2 rows + folded BN-affine/relu ----------------

template <bool TRANS>
__global__ __launch_bounds__(256) void gather_kernel(
    const unsigned int* __restrict__ hb, const float* __restrict__ sc,
    const float* __restrict__ sh, const int* __restrict__ off,
    const unsigned int* __restrict__ pck, const float* __restrict__ ct_l,
    unsigned int* __restrict__ agg, int N) {
  int wid = threadIdx.x >> 6;
  int lane = threadIdx.x & 63;
  int n = blockIdx.x * 4 + wid;
  if (n >= N) return;
  const bool act = lane < 38;
  const int u4 = lane * 4;

  float scv[8], shv[8];
  if constexpr (TRANS) {
    if (act) {
      float4 s0 = ((const float4*)(sc + lane * 8))[0];
      float4 s1 = ((const float4*)(sc + lane * 8))[1];
      float4 t0 = ((const float4*)(sh + lane * 8))[0];
      float4 t1 = ((const float4*)(sh + lane * 8))[1];
      scv[0] = s0.x; scv[1] = s0.y; scv[2] = s0.z; scv[3] = s0.w;
      scv[4] = s1.x; scv[5] = s1.y; scv[6] = s1.z; scv[7] = s1.w;
      shv[0] = t0.x; shv[1] = t0.y; shv[2] = t0.z; shv[3] = t0.w;
      shv[4] = t1.x; shv[5] = t1.y; shv[6] = t1.z; shv[7] = t1.w;
    }
  }

  float a0[4] = {0.f, 0.f, 0.f, 0.f};
  float a1[4] = {0.f, 0.f, 0.f, 0.f};

#define ACCROW(HV, CP)                                                        \
  do {                                                                        \
    float4 ca = ((const float4*)(CP))[0];                                     \
    float4 cb = ((const float4*)(CP))[1];                                     \
    float xl, xh;                                                             \
    xl = bfu_lo((HV).x); xh = bfu_hi((HV).x);                                 \
    if constexpr (TRANS) {                                                    \
      xl = fmaxf(fmaf(xl, scv[0], shv[0]), 0.f);                              \
      xh = fmaxf(fmaf(xh, scv[1], shv[1]), 0.f);                              \
    }                                                                         \
    a0[0] += xl + ca.x; a1[0] += xh + ca.y;                                   \
    xl = bfu_lo((HV).y); xh = bfu_hi((HV).y);                                 \
    if constexpr (TRANS) {                                                    \
      xl = fmaxf(fmaf(xl, scv[2], shv[2]), 0.f);                              \
      xh = fmaxf(fmaf(xh, scv[3], shv[3]), 0.f);                              \
    }                                                                         \
    a0[1] += xl + ca.z; a1[1] += xh + ca.w;                                   \
    xl = bfu_lo((HV).z); xh = bfu_hi((HV).z);                                 \
    if constexpr (TRANS) {                                                    \
      xl = fmaxf(fmaf(xl, scv[4], shv[4]), 0.f);                              \
      xh = fmaxf(fmaf(xh, scv[5], shv[5]), 0.f);                              \
    }                                                                         \
    a0[2] += xl + cb.x; a1[2] += xh + cb.y;                                   \
    xl = bfu_lo((HV).w); xh = bfu_hi((HV).w);                                 \
    if constexpr (TRANS) {                                                    \
      xl = fmaxf(fmaf(xl, scv[6], shv[6]), 0.f);                              \
      xh = fmaxf(fmaf(xh, scv[7], shv[7]), 0.f);                              \
    }                                                                         \
    a0[3] += xl + cb.z; a1[3] += xh + cb.w;                                   \
  } while (0)

  if (act) {
    uint4 hv = *(const uint4*)(hb + (size_t)n * ROWU + u4);
    ACCROW(hv, ct_l + 12 * CSTRIDE + lane * 8);
  }

  int p0 = off[n], p1 = off[n + 1];
  int p = p0;
  for (; p + 2 <= p1; p += 2) {
    unsigned int k0 = pck[p];
    unsigned int k1 = pck[p + 1];
    if (act) {
      uint4 h0 = *(const uint4*)(hb + (size_t)(k0 >> 4) * ROWU + u4);
      uint4 h1 = *(const uint4*)(hb + (size_t)(k1 >> 4) * ROWU + u4);
      ACCROW(h0, ct_l + (k0 & 15u) * CSTRIDE + lane * 8);
      ACCROW(h1, ct_l + (k1 & 15u) * CSTRIDE + lane * 8);
    }
  }
  if (p < p1) {
    unsigned int k0 = pck[p];
    if (act) {
      uint4 h0 = *(const uint4*)(hb + (size_t)(k0 >> 4) * ROWU + u4);
      ACCROW(h0, ct_l + (k0 & 15u) * CSTRIDE + lane * 8);
    }
  }
#undef ACCROW

  unsigned int* ao = agg + (size_t)n * AROWU;
  if (act) {
    uint4 o;
    o.x = packbf2(a0[0], a1[0]);
    o.y = packbf2(a0[1], a1[1]);
    o.z = packbf2(a0[2], a1[2]);
    o.w = packbf2(a0[3], a1[3]);
    *(uint4*)(ao + u4) = o;
  } else if (lane < 40) {
    *(uint4*)(ao + u4) = make_uint4(0, 0, 0, 0);
  }
}

// ---------------- BN final ----------------

__global__ void bn_final_kernel(const float* __restrict__ stats, const float* __restrict__ gamma_l,
                                const float* __restrict__ beta_l, float* __restrict__ bnsc,
                                float* __restrict__ bnsh, int N) {
  int d = threadIdx.x;
  if (d >= D_DIM) return;
  float inv_n = 1.0f / (float)N;
  float mean = stats[d] * inv_n;
  float var = stats[D_DIM + d] * inv_n - mean * mean;
  float inv = rsqrtf(var + 1e-5f);
  float sc = gamma_l[d] * inv;
  bnsc[d] = sc;
  bnsh[d] = beta_l[d] - mean * sc;
}

// ---------------- pooling: segmented reduction over sorted batch, bf16 h2 ----

__global__ void pool_seg_kernel(const unsigned short* __restrict__ h2b,
                                const float* __restrict__ sc, const float* __restrict__ sh,
                                const int* __restrict__ goff, float* __restrict__ pool) {
  int g = blockIdx.x;
  int d = threadIdx.x;
  if (d >= D_DIM) return;
  int s = goff[g], e = goff[g + 1];
  float scv = sc[d], shv = sh[d];
  float acc = 0.f;
  for (int n = s; n < e; ++n) acc += fmaf(bf16tof(h2b[(size_t)n * HSTRIDE + d]), scv, shv);
  float cnt = (float)(e - s);
  if (cnt < 1.f) cnt = 1.f;
  pool[(size_t)g * D_DIM + d] = acc / cnt;
}

// ---------------- weight pack ----------------

__global__ void wpack_kernel(const float* __restrict__ W, bf16_t* __restrict__ Th,
                             bf16_t* __restrict__ Tl, int K, int Nw) {
  int ct = blockIdx.x;
  int ks = blockIdx.y;
  int l = threadIdx.x;
  int col = ct * 16 + (l & 15);
  int kb = ks * 32 + (l >> 4) * 8;
  unsigned short hs[8], ls[8];
#pragma unroll
  for (int j = 0; j < 8; ++j) {
    int k = kb + j;
    float v = (k < K && col < Nw) ? W[(size_t)k * Nw + col] : 0.f;
    split2(v, hs[j], ls[j]);
  }
  size_t off = ((size_t)(ct * gridDim.y + ks) * 64 + l) * 8;
  *(uint4*)(Th + off) = pack8(hs);
  *(uint4*)(Tl + off) = pack8(ls);
}

// ---------------- MFMA GEMM v11: raw-barrier pipeline + LDS-repacked C store ----
// K-loop identical to v10 (round-14 proven). Epilogue: stage the 128x64 bf16
// C tile into the dead A-staging LDS (stride 72 elems -> lk groups 16 banks
// apart, 2-way free) and emit with coalesced uint4 stores (128 B/row chunks).

template <int KP, int KV, bool RELU, bool STATS>
__global__ __launch_bounds__(256, 4) void mfma_gemm11(
    const unsigned short* __restrict__ A, const bf16_t* __restrict__ Bh,
    const bf16_t* __restrict__ Bl, const float* __restrict__ bias, void* __restrict__ Cptr,
    float* __restrict__ stats, int M, int Nc, int astride, int cstride, int nx, int nyT) {
  constexpr int KSTEPS = KP / 32;
  constexpr int PLANE = 128 * 80;
  __shared__ __align__(16) char lds[2 * PLANE];

  int dd = blockIdx.x;
  int xcd = dd & 7;
  int q = dd >> 3;
  int xt = q % nx;
  int yt = (q / nx) * 8 + xcd;
  if (yt >= nyT) return;
  const int m0 = yt * 128;
  const int n0 = xt * 64;
  const int nb16 = n0 >> 4;

  const int t = threadIdx.x;
  const int w = t >> 6;
  const int lane = t & 63;
  const int wm = w >> 1, wn = w & 1;
  const int lrow = lane & 15;
  const int lk = lane >> 4;

  const int sr = t >> 1;
  const int skh = (t & 1) * 16;
  int gr = m0 + sr;
  if (gr >= M) gr = M - 1;
  const unsigned short* arow = A + (size_t)gr * astride + skh;
  const int soff = sr * 80 + (t & 1) * 32;

  const bf16_t* bp0h = Bh + ((size_t)(nb16 + wn * 2 + 0) * KSTEPS * 64 + lane) * 8;
  const bf16_t* bp1h = Bh + ((size_t)(nb16 + wn * 2 + 1) * KSTEPS * 64 + lane) * 8;
  const bf16_t* bp0l = Bl + ((size_t)(nb16 + wn * 2 + 0) * KSTEPS * 64 + lane) * 8;
  const bf16_t* bp1l = Bl + ((size_t)(nb16 + wn * 2 + 1) * KSTEPS * 64 + lane) * 8;

  f32x4 acc[4][2] = {};

  {
    uint4 v0 = ((const uint4*)arow)[0];
    uint4 v1 = ((const uint4*)arow)[1];
    *(uint4*)(lds + soff) = v0;
    *(uint4*)(lds + soff + 16) = v1;
  }
  bf16x8 bhc0 = *(const bf16x8*)(const void*)bp0h;
  bf16x8 bhc1 = *(const bf16x8*)(const void*)bp1h;
  bf16x8 blc0 = *(const bf16x8*)(const void*)bp0l;
  bf16x8 blc1 = *(const bf16x8*)(const void*)bp1l;
  __builtin_amdgcn_sched_barrier(0);
  asm volatile("s_waitcnt lgkmcnt(0)");
  __builtin_amdgcn_s_barrier();
  __builtin_amdgcn_sched_barrier(0);

#pragma unroll
  for (int kt = 0; kt < KSTEPS; ++kt) {
    const int cur = kt & 1;
    uint4 n0v, n1v;
    bf16x8 bhn0, bhn1, bln0, bln1;
    if (kt + 1 < KSTEPS) {
      const uint4* p = (const uint4*)(arow + (kt + 1) * 32);
      n0v = p[0];
      n1v = p[1];
      if (KV < KP) {
        int kg = (kt + 1) * 32 + skh;
        if (kg >= KV) n0v = make_uint4(0, 0, 0, 0);
        if (kg + 8 >= KV) n1v = make_uint4(0, 0, 0, 0);
      }
      int bs = (kt + 1) * 512;
      bhn0 = *(const bf16x8*)(const void*)(bp0h + bs);
      bhn1 = *(const bf16x8*)(const void*)(bp1h + bs);
      bln0 = *(const bf16x8*)(const void*)(bp0l + bs);
      bln1 = *(const bf16x8*)(const void*)(bp1l + bs);
    }
    const char* lbase = lds + cur * PLANE;
    bf16x8 ah[4];
#pragma unroll
    for (int i = 0; i < 4; ++i) {
      int row = wm * 64 + i * 16 + lrow;
      ah[i] = *(const bf16x8*)(const void*)(lbase + row * 80 + lk * 16);
    }
#pragma unroll
    for (int i = 0; i < 4; ++i) {
      acc[i][0] = mfma16(ah[i], bhc0, acc[i][0]);
      acc[i][0] = mfma16(ah[i], blc0, acc[i][0]);
      acc[i][1] = mfma16(ah[i], bhc1, acc[i][1]);
      acc[i][1] = mfma16(ah[i], blc1, acc[i][1]);
    }
    if (kt + 1 < KSTEPS) {
      char* sn = lds + (cur ^ 1) * PLANE + soff;
      *(uint4*)(sn) = n0v;
      *(uint4*)(sn + 16) = n1v;
      __builtin_amdgcn_sched_barrier(0);
      asm volatile("s_waitcnt lgkmcnt(0)");
      __builtin_amdgcn_s_barrier();
      __builtin_amdgcn_sched_barrier(0);
      bhc0 = bhn0;
      bhc1 = bhn1;
      blc0 = bln0;
      blc1 = bln1;
    }
  }

  // ---- epilogue: stats + stage bf16 C tile into LDS, coalesced copy-out ----
  __syncthreads();  // all waves done with A-staging LDS reads
  unsigned short* ctile = (unsigned short*)lds;  // [128][72] bf16 (144 B rows)
#pragma unroll
  for (int j = 0; j < 2; ++j) {
    const int lcol = wn * 32 + j * 16 + lrow;
    const int gcol = n0 + lcol;
    const bool colok = gcol < Nc;
    float bsv = colok ? bias[gcol] : 0.f;
    float s = 0.f, s2 = 0.f;
#pragma unroll
    for (int i = 0; i < 4; ++i) {
#pragma unroll
      for (int r4 = 0; r4 < 4; ++r4) {
        int lrowi = wm * 64 + i * 16 + lk * 4 + r4;
        float v = acc[i][j][r4] + bsv;
        if (RELU) v = fmaxf(v, 0.f);
        if constexpr (STATS) {
          if (colok && (m0 + lrowi) < M) {
            s += v;
            s2 += v * v;
          }
        }
        if (!colok) v = 0.f;
        ctile[lrowi * 72 + lcol] = __builtin_bit_cast(unsigned short, (bf16_t)v);
      }
    }
    if constexpr (STATS) {
      s += __shfl_xor(s, 16);
      s += __shfl_xor(s, 32);
      s2 += __shfl_xor(s2, 16);
      s2 += __shfl_xor(s2, 32);
      if (lk == 0 && colok) {
        atomicAdd(&stats[gcol], s);
        atomicAdd(&stats[D_DIM + gcol], s2);
      }
    }
  }
  __syncthreads();
  // coalesced copy: 128 rows x <=64 cols bf16; uint4 = 8 cols (16 B)
  int cm = cstride - n0;
  if (cm > 64) cm = 64;
  const int cmax8 = cm >> 3;  // full uint4 per row (col counts are /8 here)
  for (int idx = t; idx < 1024; idx += 256) {
    int r = idx >> 3, c8 = idx & 7;
    int grow = m0 + r;
    if (c8 < cmax8 && grow < M) {
      uint4 v = *(const uint4*)(ctile + r * 72 + c8 * 8);
      *(uint4*)((bf16_t*)Cptr + (size_t)grow * cstride + n0 + c8 * 8) = v;
    }
  }
}

// ---------------- MFMA GEMM v6 (LDS path, fp32-A feat/proj only) ----------------

template <int KP, bool RELU, bool OUT_BF16>
__global__ __launch_bounds__(256, 4) void mfma_gemm6(
    const char* __restrict__ A0, const bf16_t* __restrict__ Bh, const bf16_t* __restrict__ Bl,
    const float* __restrict__ bias, void* __restrict__ Cptr, int M, int Nc, int K, int abytes,
    int cstride, int nx, int nyT) {
  constexpr int KSTEPS = KP / 32;
  constexpr int PLANE = 128 * 80;
  __shared__ __align__(16) char lds[2 * PLANE];

  int dd = blockIdx.x;
  int xcd = dd & 7;
  int q = dd >> 3;
  int xt = q % nx;
  int yt = (q / nx) * 8 + xcd;
  if (yt >= nyT) return;
  const int m0 = yt * 128;
  const int n0 = xt * 64;
  const int nb16 = n0 >> 4;

  const int t = threadIdx.x;
  const int w = t >> 6;
  const int lane = t & 63;
  const int wm = w >> 1, wn = w & 1;
  const int lrow = lane & 15;
  const int lk = lane >> 4;

  const int sr = t >> 1;
  const int skh = (t & 1) * 16;
  const int gr = m0 + sr;
  char* sdst = lds + sr * 80 + (t & 1) * 32;

  f32x4 acc[4][2] = {};

  for (int kt = 0; kt < KSTEPS; ++kt) {
    const int kg = kt * 32 + skh;
    float va[16];
    if (gr < M && kg + 16 <= K) {
      const float4* fp = (const float4*)(A0 + (size_t)gr * abytes + kg * 4);
#pragma unroll
      for (int qd = 0; qd < 4; ++qd) {
        float4 x = fp[qd];
        va[4 * qd] = x.x;
        va[4 * qd + 1] = x.y;
        va[4 * qd + 2] = x.z;
        va[4 * qd + 3] = x.w;
      }
    } else {
#pragma unroll
      for (int j = 0; j < 16; ++j)
        va[j] = (gr < M && kg + j < K) ? *(const float*)(A0 + (size_t)gr * abytes + (kg + j) * 4)
                                       : 0.f;
    }
    unsigned short hs[16], ls[16];
#pragma unroll
    for (int j = 0; j < 16; ++j) split2(va[j], hs[j], ls[j]);
    *(uint4*)(sdst) = pack8(hs);
    *(uint4*)(sdst + 16) = pack8(hs + 8);
    *(uint4*)(sdst + PLANE) = pack8(ls);
    *(uint4*)(sdst + PLANE + 16) = pack8(ls + 8);
    __syncthreads();
    bf16x8 ah[4], al[4];
#pragma unroll
    for (int i = 0; i < 4; ++i) {
      int row = wm * 64 + i * 16 + lrow;
      ah[i] = *(const bf16x8*)(const void*)(lds + row * 80 + lk * 16);
      al[i] = *(const bf16x8*)(const void*)(lds + PLANE + row * 80 + lk * 16);
    }
#pragma unroll
    for (int j = 0; j < 2; ++j) {
      int ct16 = nb16 + wn * 2 + j;
      size_t bo = ((size_t)(ct16 * KSTEPS + kt) * 64 + lane) * 8;
      bf16x8 bh = *(const bf16x8*)(const void*)(Bh + bo);
      bf16x8 bl = *(const bf16x8*)(const void*)(Bl + bo);
#pragma unroll
      for (int i = 0; i < 4; ++i) {
        acc[i][j] = mfma16(ah[i], bh, acc[i][j]);
        acc[i][j] = mfma16(ah[i], bl, acc[i][j]);
        acc[i][j] = mfma16(al[i], bh, acc[i][j]);
      }
    }
    __syncthreads();
  }

#pragma unroll
  for (int j = 0; j < 2; ++j) {
    int gcol = n0 + wn * 32 + j * 16 + lrow;
    if (gcol >= Nc) continue;
    float bsv = bias[gcol];
#pragma unroll
    for (int i = 0; i < 4; ++i) {
#pragma unroll
      for (int r4 = 0; r4 < 4; ++r4) {
        int grow = m0 + wm * 64 + i * 16 + lk * 4 + r4;
        if (grow < M) {
          float v = acc[i][j][r4] + bsv;
          if (RELU) v = fmaxf(v, 0.f);
          if constexpr (OUT_BF16)
            ((bf16_t*)Cptr)[(size_t)grow * cstride + gcol] = (bf16_t)v;
          else
            ((float*)Cptr)[(size_t)grow * cstride + gcol] = v;
        }
      }
    }
  }
}

// ---------------- launch ----------------

extern "C" void kernel_launch(void* const* d_in, const int* in_sizes, int n_in,
                              void* d_out, int out_size, void* d_ws, size_t ws_size,
                              hipStream_t stream) {
  const int* atom = (const int*)d_in[0];
  const int* chir = (const int*)d_in[1];
  const int* eidx = (const int*)d_in[2];
  const int* btype = (const int*)d_in[3];
  const int* bdir = (const int*)d_in[4];
  const int* batch = (const int*)d_in[5];
  const float* x_emb1 = (const float*)d_in[6];
  const float* x_emb2 = (const float*)d_in[7];
  const float* ee1 = (const float*)d_in[8];
  const float* ee2 = (const float*)d_in[9];
  const float* W1 = (const float*)d_in[10];
  const float* b1 = (const float*)d_in[11];
  const float* W2 = (const float*)d_in[12];
  const float* b2 = (const float*)d_in[13];
  const float* gamma = (const float*)d_in[14];
  const float* beta = (const float*)d_in[15];
  const float* featW = (const float*)d_in[16];
  const float* featb = (const float*)d_in[17];
  const float* projW = (const float*)d_in[18];
  const float* projb = (const float*)d_in[19];

  const int N = in_sizes[0];
  const int E = in_sizes[2] / 2;
  const int PROJ = in_sizes[19];
  const int FEAT = in_sizes[17];
  const int G = out_size / PROJ;
  const int L = in_sizes[11] / (2 * D_DIM);
  const int D2 = 2 * D_DIM;  // 600

  const int* row = eidx;
  const int* col = eidx + E;

  const int CT16_1 = 40, KS_1 = 10;  // W1: K=300->KP320, N=600->640
  const int CT16_2 = 20, KS_2 = 19;  // W2: K=600->KP608, N=300->320
  const int CT16_F = 32, KS_F = 10;  // feat
  const int CT16_P = 16, KS_P = 16;  // proj
  const int SZ1 = CT16_1 * KS_1 * 512;
  const int SZ2 = CT16_2 * KS_2 * 512;
  const int SZF = CT16_F * KS_F * 512;
  const int SZP = CT16_P * KS_P * 512;

  char* ws = (char*)d_ws;
  size_t off = 0;
  auto alloc = [&](size_t bytes) -> char* {
    char* p = ws + off;
    off += (bytes + 255) & ~(size_t)255;
    return p;
  };
  // disjoint per-phase buffers: gather R3->R1, GEMM1 R1->R2, GEMM2 R2->R3
  char* R1 = alloc((size_t)N * 640);   // agg bf16 [N][320]
  char* R2 = alloc((size_t)N * 1216);  // hid bf16 [N][608]
  char* R3 = alloc((size_t)N * 608);   // h2 bf16 [N][304]
  float* CT = (float*)alloc((size_t)L * 13 * CSTRIDE * 4);
  int* EC = (int*)alloc((size_t)E * 4);
  int* DEG = (int*)alloc((size_t)N * 4);
  int* OFF = (int*)alloc((size_t)(N + 1) * 4);
  int* CUR = (int*)alloc((size_t)N * 4);
  int* BTOT = (int*)alloc(512);
  unsigned int* PCK = (unsigned int*)alloc((size_t)E * 4);
  int* GOFF = (int*)alloc((size_t)(G + 1) * 4);
  float* STATS = (float*)alloc(2 * D_DIM * 4);
  float* BNSC = (float*)alloc(D_DIM * 4);
  float* BNSH = (float*)alloc(D_DIM * 4);
  bf16_t* W1Th = (bf16_t*)alloc((size_t)L * SZ1 * 2);
  bf16_t* W1Tl = (bf16_t*)alloc((size_t)L * SZ1 * 2);
  bf16_t* W2Th = (bf16_t*)alloc((size_t)L * SZ2 * 2);
  bf16_t* W2Tl = (bf16_t*)alloc((size_t)L * SZ2 * 2);
  bf16_t* FTh = (bf16_t*)alloc((size_t)SZF * 2);
  bf16_t* FTl = (bf16_t*)alloc((size_t)SZF * 2);
  bf16_t* PTh = (bf16_t*)alloc((size_t)SZP * 2);
  bf16_t* PTl = (bf16_t*)alloc((size_t)SZP * 2);
  (void)ws_size;

  unsigned int* AGG = (unsigned int*)R1;
  char* HID = R2;
  unsigned int* H2B = (unsigned int*)R3;

  // ---- prep ----
  init_h_kernel<<<N, 256, 0, stream>>>(atom, chir, x_emb1, x_emb2, H2B);
  combo_kernel<<<L * 13, TPB, 0, stream>>>(ee1, ee2, CT);
  edge_combo_kernel<<<(E + 255) / 256, 256, 0, stream>>>(btype, bdir, EC, E);

  const int nb = (N + SBLK - 1) / SBLK;
  zero_u32_kernel<<<(N + 255) / 256, 256, 0, stream>>>((unsigned int*)DEG, N);
  csr_count_kernel<<<(E + 255) / 256, 256, 0, stream>>>(row, DEG, E);
  scan1_kernel<<<nb, SBLK, 0, stream>>>(DEG, OFF, BTOT, N);
  scan2_kernel<<<1, 128, 0, stream>>>(BTOT, OFF, N, nb);
  scan3_kernel<<<nb, SBLK, 0, stream>>>(OFF, CUR, BTOT, N);
  csr_fill_kernel<<<(E + 255) / 256, 256, 0, stream>>>(row, col, EC, CUR, PCK, E);
  goff_kernel<<<(N + 255) / 256, 256, 0, stream>>>(batch, GOFF, N, G);

  for (int l = 0; l < L; ++l) {
    wpack_kernel<<<dim3(CT16_1, KS_1), 64, 0, stream>>>(
        W1 + (size_t)l * D_DIM * D2, W1Th + (size_t)l * SZ1, W1Tl + (size_t)l * SZ1, D_DIM, D2);
    wpack_kernel<<<dim3(CT16_2, KS_2), 64, 0, stream>>>(
        W2 + (size_t)l * D2 * D_DIM, W2Th + (size_t)l * SZ2, W2Tl + (size_t)l * SZ2, D2, D_DIM);
  }
  wpack_kernel<<<dim3(CT16_F, KS_F), 64, 0, stream>>>(featW, FTh, FTl, D_DIM, FEAT);
  wpack_kernel<<<dim3(CT16_P, KS_P), 64, 0, stream>>>(projW, PTh, PTl, FEAT, PROJ);

  const int nyT = (N + 127) / 128;
  const int ny8 = ((nyT + 7) / 8) * 8;
  const int nyG = (G + 127) / 128;
  const int nyG8 = ((nyG + 7) / 8) * 8;

  for (int l = 0; l < L; ++l) {
    const float* ctl = CT + (size_t)l * 13 * CSTRIDE;
    // gather: reads H2B (R3, bf16) + folded affine; writes agg (R1)
    if (l == 0)
      gather_kernel<false><<<(N + 3) / 4, 256, 0, stream>>>(H2B, BNSC, BNSH, OFF, PCK, ctl,
                                                            AGG, N);
    else
      gather_kernel<true><<<(N + 3) / 4, 256, 0, stream>>>(H2B, BNSC, BNSH, OFF, PCK, ctl,
                                                           AGG, N);
    // hid = relu(agg @ W1 + b1) -> bf16 [N][608] into R2 (LDS-repacked store)
    mfma_gemm11<320, 320, true, false><<<10 * ny8, 256, 0, stream>>>(
        (const unsigned short*)R1, W1Th + (size_t)l * SZ1, W1Tl + (size_t)l * SZ1,
        b1 + (size_t)l * D2, HID, nullptr, N, D2, 320, 608, 10, nyT);
    // h2 = hid @ W2 + b2 -> bf16 [N][304] into R3, fused column stats
    zero_u32_kernel<<<2, 320, 0, stream>>>((unsigned int*)STATS, 2 * D_DIM);
    mfma_gemm11<608, 600, false, true><<<5 * ny8, 256, 0, stream>>>(
        (const unsigned short*)HID, W2Th + (size_t)l * SZ2, W2Tl + (size_t)l * SZ2,
        b2 + (size_t)l * D_DIM, H2B, STATS, N, D_DIM, 608, HSTRIDE, 5, nyT);
    bn_final_kernel<<<1, TPB, 0, stream>>>(STATS, gamma + (size_t)l * D_DIM,
                                           beta + (size_t)l * D_DIM, BNSC, BNSH, N);
  }

  // final h2 bf16 in R3 (last BN folded into pool); R2 free
  float* POOL = (float*)R2;
  float* FEATB = POOL + (size_t)G * D_DIM;

  pool_seg_kernel<<<G, TPB, 0, stream>>>((const unsigned short*)H2B, BNSC, BNSH, GOFF, POOL);

  mfma_gemm6<320, false, false><<<8 * nyG8, 256, 0, stream>>>(
      (const char*)POOL, FTh, FTl, featb, FEATB, G, FEAT, D_DIM, 1200, FEAT, 8, nyG);
  mfma_gemm6<512, false, false><<<4 * nyG8, 256, 0, stream>>>(
      (const char*)FEATB, PTh, PTl, projb, d_out, G, PROJ, FEAT, 2048, PROJ, 4, nyG);
}

// Round 21
// 1917.782 us; speedup vs baseline: 1.1112x; 1.0030x over previous
//
#include <hip/hip_runtime.h>
#include <hip/hip_bf16.h>

typedef __bf16 bf16_t;
typedef bf16_t bf16x8 __attribute__((ext_vector_type(8)));
typedef float f32x4 __attribute__((ext_vector_type(4)));

#define D_DIM 300
#define HSTRIDE 304   // bf16 h2 rows padded to 304 elems (608 B)
#define CSTRIDE 304   // combo table rows padded to 304 floats
#define ROWU 152      // bf16 h row = 152 u32 (304 bf16)
#define AROWU 160     // bf16 agg row = 160 u32 (320 bf16, 640 B)
#define TPB 320

__device__ inline f32x4 mfma16(bf16x8 a, bf16x8 b, f32x4 c) {
  return __builtin_amdgcn_mfma_f32_16x16x32_bf16(a, b, c, 0, 0, 0);
}

__device__ inline void split2(float x, unsigned short& h, unsigned short& l) {
  bf16_t hb = (bf16_t)x;
  float hf = (float)hb;
  bf16_t lb = (bf16_t)(x - hf);
  h = __builtin_bit_cast(unsigned short, hb);
  l = __builtin_bit_cast(unsigned short, lb);
}

__device__ inline uint4 pack8(const unsigned short* s) {
  return make_uint4((unsigned int)s[0] | ((unsigned int)s[1] << 16),
                    (unsigned int)s[2] | ((unsigned int)s[3] << 16),
                    (unsigned int)s[4] | ((unsigned int)s[5] << 16),
                    (unsigned int)s[6] | ((unsigned int)s[7] << 16));
}

__device__ inline unsigned int packbf2(float x0, float x1) {
  unsigned short a = __builtin_bit_cast(unsigned short, (bf16_t)x0);
  unsigned short b = __builtin_bit_cast(unsigned short, (bf16_t)x1);
  return (unsigned int)a | ((unsigned int)b << 16);
}

__device__ inline float bfu_lo(unsigned int u) {
  unsigned int x = u << 16;
  float f;
  __builtin_memcpy(&f, &x, 4);
  return f;
}

__device__ inline float bfu_hi(unsigned int u) {
  unsigned int x = u & 0xffff0000u;
  float f;
  __builtin_memcpy(&f, &x, 4);
  return f;
}

__device__ inline float bf16tof(unsigned short us) {
  unsigned int x = (unsigned int)us << 16;
  float f;
  __builtin_memcpy(&f, &x, 4);
  return f;
}

// ---------------- utility ----------------

__global__ void zero_u32_kernel(unsigned int* __restrict__ p, long long n) {
  long long i = (long long)blockIdx.x * blockDim.x + threadIdx.x;
  long long s = (long long)gridDim.x * blockDim.x;
  for (; i < n; i += s) p[i] = 0u;
}

// ---------------- graph prep ----------------

__global__ void init_h_kernel(const int* __restrict__ atom, const int* __restrict__ chir,
                              const float* __restrict__ e1, const float* __restrict__ e2,
                              unsigned int* __restrict__ hb) {
  int n = blockIdx.x;
  int t = threadIdx.x;
  if (t >= ROWU) return;
  int d = t * 2;
  unsigned int out = 0u;
  if (d < D_DIM) {
    int a = atom[n], c = chir[n];
    float x0 = e1[a * D_DIM + d] + e2[c * D_DIM + d];
    float x1 = e1[a * D_DIM + d + 1] + e2[c * D_DIM + d + 1];
    out = packbf2(x0, x1);
  }
  hb[(size_t)n * ROWU + t] = out;
}

__global__ void combo_kernel(const float* __restrict__ ee1, const float* __restrict__ ee2,
                             float* __restrict__ ct) {
  int l = blockIdx.x / 13, c = blockIdx.x % 13;
  int d = threadIdx.x;
  if (d >= CSTRIDE) return;
  int bt = (c < 12) ? (c / 3) : 4;
  int bd = (c < 12) ? (c % 3) : 0;
  float v = 0.f;
  if (d < D_DIM)
    v = ee1[(size_t)(l * 5 + bt) * D_DIM + d] + ee2[(size_t)(l * 3 + bd) * D_DIM + d];
  ct[((size_t)(l * 13 + c)) * CSTRIDE + d] = v;
}

__global__ void edge_combo_kernel(const int* __restrict__ bt, const int* __restrict__ bd,
                                  int* __restrict__ ec, int E) {
  int e = blockIdx.x * blockDim.x + threadIdx.x;
  if (e < E) ec[e] = bt[e] * 3 + bd[e];
}

// ---------------- CSR build (parallel hierarchical scan) ----------------

__global__ void csr_count_kernel(const int* __restrict__ row, int* __restrict__ deg, int E) {
  int e = blockIdx.x * blockDim.x + threadIdx.x;
  if (e < E) atomicAdd(&deg[row[e]], 1);
}

#define SBLK 1024
__global__ void scan1_kernel(const int* __restrict__ deg, int* __restrict__ off,
                             int* __restrict__ btot, int n) {
  __shared__ int buf[SBLK];
  int t = threadIdx.x;
  int i = blockIdx.x * SBLK + t;
  int v = (i < n) ? deg[i] : 0;
  buf[t] = v;
  __syncthreads();
#pragma unroll
  for (int s = 1; s < SBLK; s <<= 1) {
    int add = (t >= s) ? buf[t - s] : 0;
    __syncthreads();
    buf[t] += add;
    __syncthreads();
  }
  if (i < n) off[i] = buf[t] - v;
  if (t == SBLK - 1) btot[blockIdx.x] = buf[t];
}

__global__ void scan2_kernel(int* __restrict__ btot, int* __restrict__ off, int n, int nb) {
  __shared__ int buf[128];
  int t = threadIdx.x;
  int v = (t < nb) ? btot[t] : 0;
  buf[t] = v;
  __syncthreads();
#pragma unroll
  for (int s = 1; s < 128; s <<= 1) {
    int add = (t >= s) ? buf[t - s] : 0;
    __syncthreads();
    buf[t] += add;
    __syncthreads();
  }
  if (t < nb) btot[t] = buf[t] - v;
  if (t == nb - 1) off[n] = buf[t];
}

__global__ void scan3_kernel(int* __restrict__ off, int* __restrict__ cur,
                             const int* __restrict__ btot, int n) {
  int i = blockIdx.x * SBLK + threadIdx.x;
  if (i < n) {
    int v = off[i] + btot[blockIdx.x];
    off[i] = v;
    cur[i] = v;
  }
}

// fill packed edge records: pck[p] = (col << 4) | ec   (col < 2^24, ec < 13)
__global__ void csr_fill_kernel(const int* __restrict__ row, const int* __restrict__ col,
                                const int* __restrict__ ec, int* __restrict__ cur,
                                unsigned int* __restrict__ pck, int E) {
  int e = blockIdx.x * blockDim.x + threadIdx.x;
  if (e < E) {
    int r = row[e];
    int p = atomicAdd(&cur[r], 1);
    pck[p] = ((unsigned int)col[e] << 4) | (unsigned int)ec[e];
  }
}

// ---------------- graph segment offsets (batch is SORTED) ----------------

__global__ void goff_kernel(const int* __restrict__ batch, int* __restrict__ goff, int N, int G) {
  int n = blockIdx.x * blockDim.x + threadIdx.x;
  if (n >= N) return;
  if (n == 0) {
    int g1 = batch[0];
    for (int g = 0; g <= g1; ++g) goff[g] = 0;
  } else {
    int g0 = batch[n - 1], g1 = batch[n];
    for (int g = g0 + 1; g <= g1; ++g) goff[g] = n;
  }
  if (n == N - 1) {
    int g0 = batch[N - 1];
    for (int g = g0 + 1; g <= G; ++g) goff[g] = N;
  }
}

// ---------------- gather v5: 4-edge unroll for MLP, folded BN-affine/relu ----------------

template <bool TRANS>
__global__ __launch_bounds__(256) void gather_kernel(
    const unsigned int* __restrict__ hb, const float* __restrict__ sc,
    const float* __restrict__ sh, const int* __restrict__ off,
    const unsigned int* __restrict__ pck, const float* __restrict__ ct_l,
    unsigned int* __restrict__ agg, int N) {
  int wid = threadIdx.x >> 6;
  int lane = threadIdx.x & 63;
  int n = blockIdx.x * 4 + wid;
  if (n >= N) return;
  const bool act = lane < 38;
  const int u4 = lane * 4;

  float scv[8], shv[8];
  if constexpr (TRANS) {
    if (act) {
      float4 s0 = ((const float4*)(sc + lane * 8))[0];
      float4 s1 = ((const float4*)(sc + lane * 8))[1];
      float4 t0 = ((const float4*)(sh + lane * 8))[0];
      float4 t1 = ((const float4*)(sh + lane * 8))[1];
      scv[0] = s0.x; scv[1] = s0.y; scv[2] = s0.z; scv[3] = s0.w;
      scv[4] = s1.x; scv[5] = s1.y; scv[6] = s1.z; scv[7] = s1.w;
      shv[0] = t0.x; shv[1] = t0.y; shv[2] = t0.z; shv[3] = t0.w;
      shv[4] = t1.x; shv[5] = t1.y; shv[6] = t1.z; shv[7] = t1.w;
    }
  }

  float a0[4] = {0.f, 0.f, 0.f, 0.f};
  float a1[4] = {0.f, 0.f, 0.f, 0.f};

#define ACCROW(HV, CP)                                                        \
  do {                                                                        \
    float4 ca = ((const float4*)(CP))[0];                                     \
    float4 cb = ((const float4*)(CP))[1];                                     \
    float xl, xh;                                                             \
    xl = bfu_lo((HV).x); xh = bfu_hi((HV).x);                                 \
    if constexpr (TRANS) {                                                    \
      xl = fmaxf(fmaf(xl, scv[0], shv[0]), 0.f);                              \
      xh = fmaxf(fmaf(xh, scv[1], shv[1]), 0.f);                              \
    }                                                                         \
    a0[0] += xl + ca.x; a1[0] += xh + ca.y;                                   \
    xl = bfu_lo((HV).y); xh = bfu_hi((HV).y);                                 \
    if constexpr (TRANS) {                                                    \
      xl = fmaxf(fmaf(xl, scv[2], shv[2]), 0.f);                              \
      xh = fmaxf(fmaf(xh, scv[3], shv[3]), 0.f);                              \
    }                                                                         \
    a0[1] += xl + ca.z; a1[1] += xh + ca.w;                                   \
    xl = bfu_lo((HV).z); xh = bfu_hi((HV).z);                                 \
    if constexpr (TRANS) {                                                    \
      xl = fmaxf(fmaf(xl, scv[4], shv[4]), 0.f);                              \
      xh = fmaxf(fmaf(xh, scv[5], shv[5]), 0.f);                              \
    }                                                                         \
    a0[2] += xl + cb.x; a1[2] += xh + cb.y;                                   \
    xl = bfu_lo((HV).w); xh = bfu_hi((HV).w);                                 \
    if constexpr (TRANS) {                                                    \
      xl = fmaxf(fmaf(xl, scv[6], shv[6]), 0.f);                              \
      xh = fmaxf(fmaf(xh, scv[7], shv[7]), 0.f);                              \
    }                                                                         \
    a0[3] += xl + cb.z; a1[3] += xh + cb.w;                                   \
  } while (0)

  if (act) {
    uint4 hv = *(const uint4*)(hb + (size_t)n * ROWU + u4);
    ACCROW(hv, ct_l + 12 * CSTRIDE + lane * 8);
  }

  int p0 = off[n], p1 = off[n + 1];
  int p = p0;
  // 4-edge unroll: four random h rows in flight per iteration
  for (; p + 4 <= p1; p += 4) {
    unsigned int k0 = pck[p];
    unsigned int k1 = pck[p + 1];
    unsigned int k2 = pck[p + 2];
    unsigned int k3 = pck[p + 3];
    if (act) {
      uint4 h0 = *(const uint4*)(hb + (size_t)(k0 >> 4) * ROWU + u4);
      uint4 h1 = *(const uint4*)(hb + (size_t)(k1 >> 4) * ROWU + u4);
      uint4 h2 = *(const uint4*)(hb + (size_t)(k2 >> 4) * ROWU + u4);
      uint4 h3 = *(const uint4*)(hb + (size_t)(k3 >> 4) * ROWU + u4);
      ACCROW(h0, ct_l + (k0 & 15u) * CSTRIDE + lane * 8);
      ACCROW(h1, ct_l + (k1 & 15u) * CSTRIDE + lane * 8);
      ACCROW(h2, ct_l + (k2 & 15u) * CSTRIDE + lane * 8);
      ACCROW(h3, ct_l + (k3 & 15u) * CSTRIDE + lane * 8);
    }
  }
  for (; p + 2 <= p1; p += 2) {
    unsigned int k0 = pck[p];
    unsigned int k1 = pck[p + 1];
    if (act) {
      uint4 h0 = *(const uint4*)(hb + (size_t)(k0 >> 4) * ROWU + u4);
      uint4 h1 = *(const uint4*)(hb + (size_t)(k1 >> 4) * ROWU + u4);
      ACCROW(h0, ct_l + (k0 & 15u) * CSTRIDE + lane * 8);
      ACCROW(h1, ct_l + (k1 & 15u) * CSTRIDE + lane * 8);
    }
  }
  if (p < p1) {
    unsigned int k0 = pck[p];
    if (act) {
      uint4 h0 = *(const uint4*)(hb + (size_t)(k0 >> 4) * ROWU + u4);
      ACCROW(h0, ct_l + (k0 & 15u) * CSTRIDE + lane * 8);
    }
  }
#undef ACCROW

  unsigned int* ao = agg + (size_t)n * AROWU;
  if (act) {
    uint4 o;
    o.x = packbf2(a0[0], a1[0]);
    o.y = packbf2(a0[1], a1[1]);
    o.z = packbf2(a0[2], a1[2]);
    o.w = packbf2(a0[3], a1[3]);
    *(uint4*)(ao + u4) = o;
  } else if (lane < 40) {
    *(uint4*)(ao + u4) = make_uint4(0, 0, 0, 0);
  }
}

// ---------------- BN final ----------------

__global__ void bn_final_kernel(const float* __restrict__ stats, const float* __restrict__ gamma_l,
                                const float* __restrict__ beta_l, float* __restrict__ bnsc,
                                float* __restrict__ bnsh, int N) {
  int d = threadIdx.x;
  if (d >= D_DIM) return;
  float inv_n = 1.0f / (float)N;
  float mean = stats[d] * inv_n;
  float var = stats[D_DIM + d] * inv_n - mean * mean;
  float inv = rsqrtf(var + 1e-5f);
  float sc = gamma_l[d] * inv;
  bnsc[d] = sc;
  bnsh[d] = beta_l[d] - mean * sc;
}

// ---------------- pooling: segmented reduction over sorted batch, bf16 h2 ----

__global__ void pool_seg_kernel(const unsigned short* __restrict__ h2b,
                                const float* __restrict__ sc, const float* __restrict__ sh,
                                const int* __restrict__ goff, float* __restrict__ pool) {
  int g = blockIdx.x;
  int d = threadIdx.x;
  if (d >= D_DIM) return;
  int s = goff[g], e = goff[g + 1];
  float scv = sc[d], shv = sh[d];
  float acc = 0.f;
  for (int n = s; n < e; ++n) acc += fmaf(bf16tof(h2b[(size_t)n * HSTRIDE + d]), scv, shv);
  float cnt = (float)(e - s);
  if (cnt < 1.f) cnt = 1.f;
  pool[(size_t)g * D_DIM + d] = acc / cnt;
}

// ---------------- weight pack ----------------

__global__ void wpack_kernel(const float* __restrict__ W, bf16_t* __restrict__ Th,
                             bf16_t* __restrict__ Tl, int K, int Nw) {
  int ct = blockIdx.x;
  int ks = blockIdx.y;
  int l = threadIdx.x;
  int col = ct * 16 + (l & 15);
  int kb = ks * 32 + (l >> 4) * 8;
  unsigned short hs[8], ls[8];
#pragma unroll
  for (int j = 0; j < 8; ++j) {
    int k = kb + j;
    float v = (k < K && col < Nw) ? W[(size_t)k * Nw + col] : 0.f;
    split2(v, hs[j], ls[j]);
  }
  size_t off = ((size_t)(ct * gridDim.y + ks) * 64 + l) * 8;
  *(uint4*)(Th + off) = pack8(hs);
  *(uint4*)(Tl + off) = pack8(ls);
}

// ---------------- MFMA GEMM v11: raw-barrier pipeline + LDS-repacked C store ----

template <int KP, int KV, bool RELU, bool STATS>
__global__ __launch_bounds__(256, 4) void mfma_gemm11(
    const unsigned short* __restrict__ A, const bf16_t* __restrict__ Bh,
    const bf16_t* __restrict__ Bl, const float* __restrict__ bias, void* __restrict__ Cptr,
    float* __restrict__ stats, int M, int Nc, int astride, int cstride, int nx, int nyT) {
  constexpr int KSTEPS = KP / 32;
  constexpr int PLANE = 128 * 80;
  __shared__ __align__(16) char lds[2 * PLANE];

  int dd = blockIdx.x;
  int xcd = dd & 7;
  int q = dd >> 3;
  int xt = q % nx;
  int yt = (q / nx) * 8 + xcd;
  if (yt >= nyT) return;
  const int m0 = yt * 128;
  const int n0 = xt * 64;
  const int nb16 = n0 >> 4;

  const int t = threadIdx.x;
  const int w = t >> 6;
  const int lane = t & 63;
  const int wm = w >> 1, wn = w & 1;
  const int lrow = lane & 15;
  const int lk = lane >> 4;

  const int sr = t >> 1;
  const int skh = (t & 1) * 16;
  int gr = m0 + sr;
  if (gr >= M) gr = M - 1;
  const unsigned short* arow = A + (size_t)gr * astride + skh;
  const int soff = sr * 80 + (t & 1) * 32;

  const bf16_t* bp0h = Bh + ((size_t)(nb16 + wn * 2 + 0) * KSTEPS * 64 + lane) * 8;
  const bf16_t* bp1h = Bh + ((size_t)(nb16 + wn * 2 + 1) * KSTEPS * 64 + lane) * 8;
  const bf16_t* bp0l = Bl + ((size_t)(nb16 + wn * 2 + 0) * KSTEPS * 64 + lane) * 8;
  const bf16_t* bp1l = Bl + ((size_t)(nb16 + wn * 2 + 1) * KSTEPS * 64 + lane) * 8;

  f32x4 acc[4][2] = {};

  {
    uint4 v0 = ((const uint4*)arow)[0];
    uint4 v1 = ((const uint4*)arow)[1];
    *(uint4*)(lds + soff) = v0;
    *(uint4*)(lds + soff + 16) = v1;
  }
  bf16x8 bhc0 = *(const bf16x8*)(const void*)bp0h;
  bf16x8 bhc1 = *(const bf16x8*)(const void*)bp1h;
  bf16x8 blc0 = *(const bf16x8*)(const void*)bp0l;
  bf16x8 blc1 = *(const bf16x8*)(const void*)bp1l;
  __builtin_amdgcn_sched_barrier(0);
  asm volatile("s_waitcnt lgkmcnt(0)");
  __builtin_amdgcn_s_barrier();
  __builtin_amdgcn_sched_barrier(0);

#pragma unroll
  for (int kt = 0; kt < KSTEPS; ++kt) {
    const int cur = kt & 1;
    uint4 n0v, n1v;
    bf16x8 bhn0, bhn1, bln0, bln1;
    if (kt + 1 < KSTEPS) {
      const uint4* p = (const uint4*)(arow + (kt + 1) * 32);
      n0v = p[0];
      n1v = p[1];
      if (KV < KP) {
        int kg = (kt + 1) * 32 + skh;
        if (kg >= KV) n0v = make_uint4(0, 0, 0, 0);
        if (kg + 8 >= KV) n1v = make_uint4(0, 0, 0, 0);
      }
      int bs = (kt + 1) * 512;
      bhn0 = *(const bf16x8*)(const void*)(bp0h + bs);
      bhn1 = *(const bf16x8*)(const void*)(bp1h + bs);
      bln0 = *(const bf16x8*)(const void*)(bp0l + bs);
      bln1 = *(const bf16x8*)(const void*)(bp1l + bs);
    }
    const char* lbase = lds + cur * PLANE;
    bf16x8 ah[4];
#pragma unroll
    for (int i = 0; i < 4; ++i) {
      int row = wm * 64 + i * 16 + lrow;
      ah[i] = *(const bf16x8*)(const void*)(lbase + row * 80 + lk * 16);
    }
#pragma unroll
    for (int i = 0; i < 4; ++i) {
      acc[i][0] = mfma16(ah[i], bhc0, acc[i][0]);
      acc[i][0] = mfma16(ah[i], blc0, acc[i][0]);
      acc[i][1] = mfma16(ah[i], bhc1, acc[i][1]);
      acc[i][1] = mfma16(ah[i], blc1, acc[i][1]);
    }
    if (kt + 1 < KSTEPS) {
      char* sn = lds + (cur ^ 1) * PLANE + soff;
      *(uint4*)(sn) = n0v;
      *(uint4*)(sn + 16) = n1v;
      __builtin_amdgcn_sched_barrier(0);
      asm volatile("s_waitcnt lgkmcnt(0)");
      __builtin_amdgcn_s_barrier();
      __builtin_amdgcn_sched_barrier(0);
      bhc0 = bhn0;
      bhc1 = bhn1;
      blc0 = bln0;
      blc1 = bln1;
    }
  }

  // ---- epilogue: stats + stage bf16 C tile into LDS, coalesced copy-out ----
  __syncthreads();
  unsigned short* ctile = (unsigned short*)lds;  // [128][72] bf16
#pragma unroll
  for (int j = 0; j < 2; ++j) {
    const int lcol = wn * 32 + j * 16 + lrow;
    const int gcol = n0 + lcol;
    const bool colok = gcol < Nc;
    float bsv = colok ? bias[gcol] : 0.f;
    float s = 0.f, s2 = 0.f;
#pragma unroll
    for (int i = 0; i < 4; ++i) {
#pragma unroll
      for (int r4 = 0; r4 < 4; ++r4) {
        int lrowi = wm * 64 + i * 16 + lk * 4 + r4;
        float v = acc[i][j][r4] + bsv;
        if (RELU) v = fmaxf(v, 0.f);
        if constexpr (STATS) {
          if (colok && (m0 + lrowi) < M) {
            s += v;
            s2 += v * v;
          }
        }
        if (!colok) v = 0.f;
        ctile[lrowi * 72 + lcol] = __builtin_bit_cast(unsigned short, (bf16_t)v);
      }
    }
    if constexpr (STATS) {
      s += __shfl_xor(s, 16);
      s += __shfl_xor(s, 32);
      s2 += __shfl_xor(s2, 16);
      s2 += __shfl_xor(s2, 32);
      if (lk == 0 && colok) {
        atomicAdd(&stats[gcol], s);
        atomicAdd(&stats[D_DIM + gcol], s2);
      }
    }
  }
  __syncthreads();
  int cm = cstride - n0;
  if (cm > 64) cm = 64;
  const int cmax8 = cm >> 3;
  for (int idx = t; idx < 1024; idx += 256) {
    int r = idx >> 3, c8 = idx & 7;
    int grow = m0 + r;
    if (c8 < cmax8 && grow < M) {
      uint4 v = *(const uint4*)(ctile + r * 72 + c8 * 8);
      *(uint4*)((bf16_t*)Cptr + (size_t)grow * cstride + n0 + c8 * 8) = v;
    }
  }
}

// ---------------- MFMA GEMM v6 (LDS path, fp32-A feat/proj only) ----------------

template <int KP, bool RELU, bool OUT_BF16>
__global__ __launch_bounds__(256, 4) void mfma_gemm6(
    const char* __restrict__ A0, const bf16_t* __restrict__ Bh, const bf16_t* __restrict__ Bl,
    const float* __restrict__ bias, void* __restrict__ Cptr, int M, int Nc, int K, int abytes,
    int cstride, int nx, int nyT) {
  constexpr int KSTEPS = KP / 32;
  constexpr int PLANE = 128 * 80;
  __shared__ __align__(16) char lds[2 * PLANE];

  int dd = blockIdx.x;
  int xcd = dd & 7;
  int q = dd >> 3;
  int xt = q % nx;
  int yt = (q / nx) * 8 + xcd;
  if (yt >= nyT) return;
  const int m0 = yt * 128;
  const int n0 = xt * 64;
  const int nb16 = n0 >> 4;

  const int t = threadIdx.x;
  const int w = t >> 6;
  const int lane = t & 63;
  const int wm = w >> 1, wn = w & 1;
  const int lrow = lane & 15;
  const int lk = lane >> 4;

  const int sr = t >> 1;
  const int skh = (t & 1) * 16;
  const int gr = m0 + sr;
  char* sdst = lds + sr * 80 + (t & 1) * 32;

  f32x4 acc[4][2] = {};

  for (int kt = 0; kt < KSTEPS; ++kt) {
    const int kg = kt * 32 + skh;
    float va[16];
    if (gr < M && kg + 16 <= K) {
      const float4* fp = (const float4*)(A0 + (size_t)gr * abytes + kg * 4);
#pragma unroll
      for (int qd = 0; qd < 4; ++qd) {
        float4 x = fp[qd];
        va[4 * qd] = x.x;
        va[4 * qd + 1] = x.y;
        va[4 * qd + 2] = x.z;
        va[4 * qd + 3] = x.w;
      }
    } else {
#pragma unroll
      for (int j = 0; j < 16; ++j)
        va[j] = (gr < M && kg + j < K) ? *(const float*)(A0 + (size_t)gr * abytes + (kg + j) * 4)
                                       : 0.f;
    }
    unsigned short hs[16], ls[16];
#pragma unroll
    for (int j = 0; j < 16; ++j) split2(va[j], hs[j], ls[j]);
    *(uint4*)(sdst) = pack8(hs);
    *(uint4*)(sdst + 16) = pack8(hs + 8);
    *(uint4*)(sdst + PLANE) = pack8(ls);
    *(uint4*)(sdst + PLANE + 16) = pack8(ls + 8);
    __syncthreads();
    bf16x8 ah[4], al[4];
#pragma unroll
    for (int i = 0; i < 4; ++i) {
      int row = wm * 64 + i * 16 + lrow;
      ah[i] = *(const bf16x8*)(const void*)(lds + row * 80 + lk * 16);
      al[i] = *(const bf16x8*)(const void*)(lds + PLANE + row * 80 + lk * 16);
    }
#pragma unroll
    for (int j = 0; j < 2; ++j) {
      int ct16 = nb16 + wn * 2 + j;
      size_t bo = ((size_t)(ct16 * KSTEPS + kt) * 64 + lane) * 8;
      bf16x8 bh = *(const bf16x8*)(const void*)(Bh + bo);
      bf16x8 bl = *(const bf16x8*)(const void*)(Bl + bo);
#pragma unroll
      for (int i = 0; i < 4; ++i) {
        acc[i][j] = mfma16(ah[i], bh, acc[i][j]);
        acc[i][j] = mfma16(ah[i], bl, acc[i][j]);
        acc[i][j] = mfma16(al[i], bh, acc[i][j]);
      }
    }
    __syncthreads();
  }

#pragma unroll
  for (int j = 0; j < 2; ++j) {
    int gcol = n0 + wn * 32 + j * 16 + lrow;
    if (gcol >= Nc) continue;
    float bsv = bias[gcol];
#pragma unroll
    for (int i = 0; i < 4; ++i) {
#pragma unroll
      for (int r4 = 0; r4 < 4; ++r4) {
        int grow = m0 + wm * 64 + i * 16 + lk * 4 + r4;
        if (grow < M) {
          float v = acc[i][j][r4] + bsv;
          if (RELU) v = fmaxf(v, 0.f);
          if constexpr (OUT_BF16)
            ((bf16_t*)Cptr)[(size_t)grow * cstride + gcol] = (bf16_t)v;
          else
            ((float*)Cptr)[(size_t)grow * cstride + gcol] = v;
        }
      }
    }
  }
}

// ---------------- launch ----------------

extern "C" void kernel_launch(void* const* d_in, const int* in_sizes, int n_in,
                              void* d_out, int out_size, void* d_ws, size_t ws_size,
                              hipStream_t stream) {
  const int* atom = (const int*)d_in[0];
  const int* chir = (const int*)d_in[1];
  const int* eidx = (const int*)d_in[2];
  const int* btype = (const int*)d_in[3];
  const int* bdir = (const int*)d_in[4];
  const int* batch = (const int*)d_in[5];
  const float* x_emb1 = (const float*)d_in[6];
  const float* x_emb2 = (const float*)d_in[7];
  const float* ee1 = (const float*)d_in[8];
  const float* ee2 = (const float*)d_in[9];
  const float* W1 = (const float*)d_in[10];
  const float* b1 = (const float*)d_in[11];
  const float* W2 = (const float*)d_in[12];
  const float* b2 = (const float*)d_in[13];
  const float* gamma = (const float*)d_in[14];
  const float* beta = (const float*)d_in[15];
  const float* featW = (const float*)d_in[16];
  const float* featb = (const float*)d_in[17];
  const float* projW = (const float*)d_in[18];
  const float* projb = (const float*)d_in[19];

  const int N = in_sizes[0];
  const int E = in_sizes[2] / 2;
  const int PROJ = in_sizes[19];
  const int FEAT = in_sizes[17];
  const int G = out_size / PROJ;
  const int L = in_sizes[11] / (2 * D_DIM);
  const int D2 = 2 * D_DIM;  // 600

  const int* row = eidx;
  const int* col = eidx + E;

  const int CT16_1 = 40, KS_1 = 10;  // W1: K=300->KP320, N=600->640
  const int CT16_2 = 20, KS_2 = 19;  // W2: K=600->KP608, N=300->320
  const int CT16_F = 32, KS_F = 10;  // feat
  const int CT16_P = 16, KS_P = 16;  // proj
  const int SZ1 = CT16_1 * KS_1 * 512;
  const int SZ2 = CT16_2 * KS_2 * 512;
  const int SZF = CT16_F * KS_F * 512;
  const int SZP = CT16_P * KS_P * 512;

  char* ws = (char*)d_ws;
  size_t off = 0;
  auto alloc = [&](size_t bytes) -> char* {
    char* p = ws + off;
    off += (bytes + 255) & ~(size_t)255;
    return p;
  };
  char* R1 = alloc((size_t)N * 640);   // agg bf16 [N][320]
  char* R2 = alloc((size_t)N * 1216);  // hid bf16 [N][608]
  char* R3 = alloc((size_t)N * 608);   // h2 bf16 [N][304]
  float* CT = (float*)alloc((size_t)L * 13 * CSTRIDE * 4);
  int* EC = (int*)alloc((size_t)E * 4);
  int* DEG = (int*)alloc((size_t)N * 4);
  int* OFF = (int*)alloc((size_t)(N + 1) * 4);
  int* CUR = (int*)alloc((size_t)N * 4);
  int* BTOT = (int*)alloc(512);
  unsigned int* PCK = (unsigned int*)alloc((size_t)E * 4);
  int* GOFF = (int*)alloc((size_t)(G + 1) * 4);
  float* STATS = (float*)alloc(2 * D_DIM * 4);
  float* BNSC = (float*)alloc(D_DIM * 4);
  float* BNSH = (float*)alloc(D_DIM * 4);
  bf16_t* W1Th = (bf16_t*)alloc((size_t)L * SZ1 * 2);
  bf16_t* W1Tl = (bf16_t*)alloc((size_t)L * SZ1 * 2);
  bf16_t* W2Th = (bf16_t*)alloc((size_t)L * SZ2 * 2);
  bf16_t* W2Tl = (bf16_t*)alloc((size_t)L * SZ2 * 2);
  bf16_t* FTh = (bf16_t*)alloc((size_t)SZF * 2);
  bf16_t* FTl = (bf16_t*)alloc((size_t)SZF * 2);
  bf16_t* PTh = (bf16_t*)alloc((size_t)SZP * 2);
  bf16_t* PTl = (bf16_t*)alloc((size_t)SZP * 2);
  (void)ws_size;

  unsigned int* AGG = (unsigned int*)R1;
  char* HID = R2;
  unsigned int* H2B = (unsigned int*)R3;

  // ---- prep ----
  init_h_kernel<<<N, 256, 0, stream>>>(atom, chir, x_emb1, x_emb2, H2B);
  combo_kernel<<<L * 13, TPB, 0, stream>>>(ee1, ee2, CT);
  edge_combo_kernel<<<(E + 255) / 256, 256, 0, stream>>>(btype, bdir, EC, E);

  const int nb = (N + SBLK - 1) / SBLK;
  zero_u32_kernel<<<(N + 255) / 256, 256, 0, stream>>>((unsigned int*)DEG, N);
  csr_count_kernel<<<(E + 255) / 256, 256, 0, stream>>>(row, DEG, E);
  scan1_kernel<<<nb, SBLK, 0, stream>>>(DEG, OFF, BTOT, N);
  scan2_kernel<<<1, 128, 0, stream>>>(BTOT, OFF, N, nb);
  scan3_kernel<<<nb, SBLK, 0, stream>>>(OFF, CUR, BTOT, N);
  csr_fill_kernel<<<(E + 255) / 256, 256, 0, stream>>>(row, col, EC, CUR, PCK, E);
  goff_kernel<<<(N + 255) / 256, 256, 0, stream>>>(batch, GOFF, N, G);

  for (int l = 0; l < L; ++l) {
    wpack_kernel<<<dim3(CT16_1, KS_1), 64, 0, stream>>>(
        W1 + (size_t)l * D_DIM * D2, W1Th + (size_t)l * SZ1, W1Tl + (size_t)l * SZ1, D_DIM, D2);
    wpack_kernel<<<dim3(CT16_2, KS_2), 64, 0, stream>>>(
        W2 + (size_t)l * D2 * D_DIM, W2Th + (size_t)l * SZ2, W2Tl + (size_t)l * SZ2, D2, D_DIM);
  }
  wpack_kernel<<<dim3(CT16_F, KS_F), 64, 0, stream>>>(featW, FTh, FTl, D_DIM, FEAT);
  wpack_kernel<<<dim3(CT16_P, KS_P), 64, 0, stream>>>(projW, PTh, PTl, FEAT, PROJ);

  const int nyT = (N + 127) / 128;
  const int ny8 = ((nyT + 7) / 8) * 8;
  const int nyG = (G + 127) / 128;
  const int nyG8 = ((nyG + 7) / 8) * 8;

  for (int l = 0; l < L; ++l) {
    const float* ctl = CT + (size_t)l * 13 * CSTRIDE;
    if (l == 0)
      gather_kernel<false><<<(N + 3) / 4, 256, 0, stream>>>(H2B, BNSC, BNSH, OFF, PCK, ctl,
                                                            AGG, N);
    else
      gather_kernel<true><<<(N + 3) / 4, 256, 0, stream>>>(H2B, BNSC, BNSH, OFF, PCK, ctl,
                                                           AGG, N);
    mfma_gemm11<320, 320, true, false><<<10 * ny8, 256, 0, stream>>>(
        (const unsigned short*)R1, W1Th + (size_t)l * SZ1, W1Tl + (size_t)l * SZ1,
        b1 + (size_t)l * D2, HID, nullptr, N, D2, 320, 608, 10, nyT);
    zero_u32_kernel<<<2, 320, 0, stream>>>((unsigned int*)STATS, 2 * D_DIM);
    mfma_gemm11<608, 600, false, true><<<5 * ny8, 256, 0, stream>>>(
        (const unsigned short*)HID, W2Th + (size_t)l * SZ2, W2Tl + (size_t)l * SZ2,
        b2 + (size_t)l * D_DIM, H2B, STATS, N, D_DIM, 608, HSTRIDE, 5, nyT);
    bn_final_kernel<<<1, TPB, 0, stream>>>(STATS, gamma + (size_t)l * D_DIM,
                                           beta + (size_t)l * D_DIM, BNSC, BNSH, N);
  }

  // final h2 bf16 in R3 (last BN folded into pool); R2 free
  float* POOL = (float*)R2;
  float* FEATB = POOL + (size_t)G * D_DIM;

  pool_seg_kernel<<<G, TPB, 0, stream>>>((const unsigned short*)H2B, BNSC, BNSH, GOFF, POOL);

  mfma_gemm6<320, false, false><<<8 * nyG8, 256, 0, stream>>>(
      (const char*)POOL, FTh, FTl, featb, FEATB, G, FEAT, D_DIM, 1200, FEAT, 8, nyG);
  mfma_gemm6<512, false, false><<<4 * nyG8, 256, 0, stream>>>(
      (const char*)FEATB, PTh, PTl, projb, d_out, G, PROJ, FEAT, 2048, PROJ, 4, nyG);
}